// Round 3
// baseline (9470.231 us; speedup 1.0000x reference)
//
#include <hip/hip_runtime.h>
#include <hip/hip_bf16.h>

typedef unsigned short u16;
typedef unsigned int   u32;
typedef short bf16x8 __attribute__((ext_vector_type(8)));
typedef float f32x4  __attribute__((ext_vector_type(4)));

#define NN 100000
#define EE 800000

#define MFMA16(a,b,c) __builtin_amdgcn_mfma_f32_16x16x32_bf16(a,b,c,0,0,0)

__device__ __forceinline__ float b2f(u16 u) {
    u32 x = ((u32)u) << 16;
    return __uint_as_float(x);
}
__device__ __forceinline__ u16 f2b(float f) {
    __hip_bfloat16 h = __float2bfloat16(f);
    return *reinterpret_cast<u16*>(&h);
}
template<int BF16>
__device__ __forceinline__ float ldf(const void* p, long idx) {
    if (BF16) return b2f(((const u16*)p)[idx]);
    return ((const float*)p)[idx];
}
__device__ __forceinline__ float bcastf(float v, int l) {
    return __uint_as_float(__builtin_amdgcn_readlane(__float_as_uint(v), l));
}

// dtype detector: bf16 stream => ~all u16 words have plausible bf16 exponent.
__global__ void k_detect(const void* __restrict__ pos, int* __restrict__ flag) {
    if (threadIdx.x == 0 && blockIdx.x == 0) {
        const u16* p = (const u16*)pos;
        int cnt = 0;
        for (int i = 0; i < 256; ++i) {
            int e = (p[i] >> 7) & 0xFF;
            if (e >= 100 && e <= 140) cnt++;
        }
        flag[0] = (cnt >= 200) ? 1 : 0;
    }
}

// ---------------- common prologue kernels ----------------
template<int BF16>
__device__ __forceinline__ void embed_body(const void* pos, const int* z,
                                           const void* emb, float* x) {
    int gid = blockIdx.x * 256 + threadIdx.x;
    int i = gid >> 6, f = gid & 63;
    float v;
    if (f < 3) v = ldf<BF16>(pos, (long)i * 3 + f);
    else       v = ldf<BF16>(emb, (long)z[i] * 61 + (f - 3));
    x[gid] = v;
}
__global__ __launch_bounds__(256) void k_embed(const void* pos, const int* z,
                                               const void* emb, float* x,
                                               const int* flag) {
    if (flag[0]) embed_body<1>(pos, z, emb, x);
    else         embed_body<0>(pos, z, emb, x);
}

// out = (relu_in? relu(x):x) @ W ; also writes bf16 mirror hbo
template<int BF16>
__device__ __forceinline__ void proj_body(const float* x, float* out, u16* hbo,
                                          const void* W, int relu_in) {
    int node = blockIdx.x * 4 + (threadIdx.x >> 6);
    int j = threadIdx.x & 63;
    float v = x[node * 64 + j];
    if (relu_in) v = fmaxf(v, 0.f);
    float acc = 0.f;
#pragma unroll
    for (int k = 0; k < 64; ++k)
        acc += bcastf(v, k) * ldf<BF16>(W, k * 64 + j);
    out[node * 64 + j] = acc;
    hbo[node * 64 + j] = f2b(acc);
}
__global__ __launch_bounds__(256) void k_proj(const float* x, float* out, u16* hbo,
                                              const void* W, int relu_in,
                                              const int* flag) {
    if (flag[0]) proj_body<1>(x, out, hbo, W, relu_in);
    else         proj_body<0>(x, out, hbo, W, relu_in);
}

template<int BF16>
__device__ __forceinline__ void d2_body(const void* pos, const int* src,
                                        const int* dst, float* d2) {
    int e = blockIdx.x * 256 + threadIdx.x;
    if (e >= EE) return;
    int s = src[e], d = dst[e];
    float dx = ldf<BF16>(pos, (long)s * 3 + 0) - ldf<BF16>(pos, (long)d * 3 + 0);
    float dy = ldf<BF16>(pos, (long)s * 3 + 1) - ldf<BF16>(pos, (long)d * 3 + 1);
    float dz = ldf<BF16>(pos, (long)s * 3 + 2) - ldf<BF16>(pos, (long)d * 3 + 2);
    d2[e] = dx * dx + dy * dy + dz * dz;
}
__global__ __launch_bounds__(256) void k_d2(const void* pos, const int* src,
                                            const int* dst, float* d2,
                                            const int* flag) {
    if (flag[0]) d2_body<1>(pos, src, dst, d2);
    else         d2_body<0>(pos, src, dst, d2);
}

// ---------------- CSR build ----------------
__global__ __launch_bounds__(256) void k_deg(const int* __restrict__ dst,
                                             int* __restrict__ deg) {
    int e = blockIdx.x * 256 + threadIdx.x;
    if (e < EE) atomicAdd(&deg[dst[e]], 1);
}

__global__ __launch_bounds__(1024) void k_scan(const int* __restrict__ deg,
                                               int* __restrict__ rowptr) {
    __shared__ int s[1024];
    int carry = 0;
    for (int base = 0; base < NN; base += 1024) {
        int i = base + (int)threadIdx.x;
        int v = (i < NN) ? deg[i] : 0;
        s[threadIdx.x] = v;
        __syncthreads();
        for (int off = 1; off < 1024; off <<= 1) {
            int t = (threadIdx.x >= (unsigned)off) ? s[threadIdx.x - off] : 0;
            __syncthreads();
            s[threadIdx.x] += t;
            __syncthreads();
        }
        int incl = s[threadIdx.x];
        if (i < NN) rowptr[i] = carry + incl - v;
        carry += s[1023];
        __syncthreads();
    }
    if (threadIdx.x == 0) rowptr[NN] = carry;
}

__global__ __launch_bounds__(256) void k_scatter(const int* __restrict__ dst,
                                                 int* __restrict__ cursor,
                                                 int* __restrict__ eidx) {
    int e = blockIdx.x * 256 + threadIdx.x;
    if (e < EE) {
        int p = atomicAdd(&cursor[dst[e]], 1);
        eidx[p] = e;
    }
}

// CSR-order src and d2
__global__ __launch_bounds__(256) void k_reorder(const int* __restrict__ eidx,
                                                 const int* __restrict__ src,
                                                 const float* __restrict__ d2,
                                                 int* __restrict__ srcc,
                                                 float* __restrict__ d2c) {
    int t = blockIdx.x * 256 + threadIdx.x;
    if (t < EE) {
        int e = eidx[t];
        srcc[t] = src[e];
        d2c[t] = d2[e];
    }
}

// ---------------- weight swizzle into MFMA B-frag order ----------------
// per layer L (0..7): [W1s 8192 u16][W2s 4096][W3s 8192], frag f: 64 lanes x 8 elems
// elem j of (f,lane): W[ks*32 + (lane>>4)*8 + j][nt*16 + (lane&15)], f = ks*4+nt
__global__ __launch_bounds__(256) void k_swz(const u16* t1W1, const u16* t1W2, const u16* t1W3,
                                             const u16* t2W1, const u16* t2W2, const u16* t2W3,
                                             u16* Ws) {
    int gid = blockIdx.x * 256 + threadIdx.x;   // 8*20480 threads exactly
    int L = gid / 20480;
    int r = gid % 20480;
    const u16* W1 = (L < 4 ? t1W1 : t2W1) + (L & 3) * 129 * 64;
    const u16* W2 = (L < 4 ? t1W2 : t2W2) + (L & 3) * 64 * 64;
    const u16* W3 = (L < 4 ? t1W3 : t2W3) + (L & 3) * 128 * 64;
    u16 v;
    if (r < 8192) {
        int f = r >> 9, e = r & 511, lane = e >> 3, j = e & 7;
        int row = (f >> 2) * 32 + (lane >> 4) * 8 + j;
        int col = (f & 3) * 16 + (lane & 15);
        v = W1[row * 64 + col];
    } else if (r < 12288) {
        int rr = r - 8192;
        int f = rr >> 9, e = rr & 511, lane = e >> 3, j = e & 7;
        int row = (f >> 2) * 32 + (lane >> 4) * 8 + j;
        int col = (f & 3) * 16 + (lane & 15);
        v = W2[row * 64 + col];
    } else {
        int rr = r - 12288;
        int f = rr >> 9, e = rr & 511, lane = e >> 3, j = e & 7;
        int row = (f >> 2) * 32 + (lane >> 4) * 8 + j;
        int col = (f & 3) * 16 + (lane & 15);
        v = W3[row * 64 + col];
    }
    Ws[gid] = v;
}

// ---------------- MFMA edge kernel: one wave per dst node ----------------
__global__ __launch_bounds__(256) void k_edges_mfma(const u16* __restrict__ hb,
                                                    u16* __restrict__ aggb,
                                                    const float* __restrict__ d2c,
                                                    const int* __restrict__ rowptr,
                                                    const int* __restrict__ srcc,
                                                    const u16* __restrict__ Wsl,
                                                    const u16* __restrict__ W1raw,
                                                    const u16* __restrict__ b1,
                                                    const u16* __restrict__ b2,
                                                    const int* __restrict__ flag) {
    __shared__ u16 h1s[4][16 * 72];
    if (!flag[0]) return;
    int w = threadIdx.x >> 6, lane = threadIdx.x & 63;
    int node = blockIdx.x * 4 + w;
    int c = lane & 15, g = lane >> 4;
    u16* hl = h1s[w];

    const bf16x8* WF = (const bf16x8*)Wsl;   // W1 frags [0..15], W2 frags at +1024
    // stationary W1 (h_src half) and W2 frags
    bf16x8 w1a[4], w1b[4], w2a[4], w2b[4];
#pragma unroll
    for (int nt = 0; nt < 4; ++nt) {
        w1a[nt] = WF[(0 * 4 + nt) * 64 + lane];
        w1b[nt] = WF[(1 * 4 + nt) * 64 + lane];
        w2a[nt] = WF[1024 + (0 * 4 + nt) * 64 + lane];
        w2b[nt] = WF[1024 + (1 * 4 + nt) * 64 + lane];
    }
    float b1c[4], wdc[4];
#pragma unroll
    for (int nt = 0; nt < 4; ++nt) {
        b1c[nt] = b2f(b1[nt * 16 + c]);
        wdc[nt] = b2f(W1raw[128 * 64 + nt * 16 + c]);   // d2 weight row
    }
    float b2c = b2f(b2[lane]);

    // h_dst half of GEMM1: rows identical -> one value per col, once per node
    const bf16x8* hp = (const bf16x8*)(hb + (long)node * 64);
    bf16x8 Ad0 = hp[g], Ad1 = hp[g + 4];
    f32x4 z = {0.f, 0.f, 0.f, 0.f};
    float accd[4];
#pragma unroll
    for (int nt = 0; nt < 4; ++nt) {
        f32x4 t = MFMA16(Ad0, WF[(2 * 4 + nt) * 64 + lane], z);
        t = MFMA16(Ad1, WF[(3 * 4 + nt) * 64 + lane], t);
        accd[nt] = t[0];
    }

    int e0 = rowptr[node], e1 = rowptr[node + 1];
    f32x4 acc2[4] = {z, z, z, z};

    for (int te = e0; te < e1; te += 16) {
        int t = te + c;
        if (t > e1 - 1) t = e1 - 1;
        int s = srcc[t];
        const bf16x8* sp = (const bf16x8*)(hb + (long)s * 64);
        bf16x8 A0 = sp[g], A1 = sp[g + 4];
        float dq[4];
#pragma unroll
        for (int r = 0; r < 4; ++r) dq[r] = d2c[te + 4 * g + r];
        int rem = e1 - te;
        f32x4 a1[4];
#pragma unroll
        for (int nt = 0; nt < 4; ++nt) {
            f32x4 ci;
#pragma unroll
            for (int r = 0; r < 4; ++r) ci[r] = b1c[nt] + accd[nt] + dq[r] * wdc[nt];
            a1[nt] = MFMA16(A0, w1a[nt], ci);
            a1[nt] = MFMA16(A1, w1b[nt], a1[nt]);
        }
        // relu + pad-mask, C-layout -> row-major LDS [edge][72]
#pragma unroll
        for (int nt = 0; nt < 4; ++nt)
#pragma unroll
            for (int r = 0; r < 4; ++r) {
                int m = 4 * g + r;
                float v = (m < rem) ? fmaxf(a1[nt][r], 0.f) : 0.f;
                hl[m * 72 + nt * 16 + c] = f2b(v);
            }
        bf16x8 F0 = *(const bf16x8*)(hl + c * 72 + g * 8);
        bf16x8 F1 = *(const bf16x8*)(hl + c * 72 + g * 8 + 32);
#pragma unroll
        for (int nt = 0; nt < 4; ++nt) {
            acc2[nt] = MFMA16(F0, w2a[nt], acc2[nt]);
            acc2[nt] = MFMA16(F1, w2b[nt], acc2[nt]);
        }
    }

    float deg = (float)(e1 - e0);
    float sv[4];
#pragma unroll
    for (int nt = 0; nt < 4; ++nt) {
        float s = acc2[nt][0] + acc2[nt][1] + acc2[nt][2] + acc2[nt][3];
        s += __shfl_xor(s, 16);
        s += __shfl_xor(s, 32);
        sv[nt] = s;
    }
    float v = sv[0];
    v = (g == 1) ? sv[1] : v;
    v = (g == 2) ? sv[2] : v;
    v = (g == 3) ? sv[3] : v;
    v += deg * b2c;
    aggb[(long)node * 64 + lane] = f2b(v);
}

// ---------------- MFMA node update: 16 nodes per wave ----------------
__global__ __launch_bounds__(256) void k_node_mfma(float* __restrict__ h,
                                                   u16* __restrict__ hb,
                                                   const u16* __restrict__ aggb,
                                                   const u16* __restrict__ Wsl,
                                                   const u16* __restrict__ b3,
                                                   const int* __restrict__ flag) {
    if (!flag[0]) return;
    int tile = blockIdx.x * 4 + (threadIdx.x >> 6);
    if (tile >= NN / 16) return;            // 6250 tiles exactly
    int lane = threadIdx.x & 63;
    int c = lane & 15, g = lane >> 4;
    int n0 = tile * 16;

    const bf16x8* WF = (const bf16x8*)(Wsl + 24576);   // W3 frags
    bf16x8 wf[16];
#pragma unroll
    for (int f = 0; f < 16; ++f) wf[f] = WF[f * 64 + lane];

    int nr = n0 + c;
    const bf16x8* hp = (const bf16x8*)(hb + (long)nr * 64);
    const bf16x8* ap = (const bf16x8*)(aggb + (long)nr * 64);
    bf16x8 Ah0 = hp[g], Ah1 = hp[g + 4];
    bf16x8 Aa0 = ap[g], Aa1 = ap[g + 4];

#pragma unroll
    for (int nt = 0; nt < 4; ++nt) {
        float bv = b2f(b3[nt * 16 + c]);
        f32x4 acc = {bv, bv, bv, bv};
        acc = MFMA16(Ah0, wf[0 * 4 + nt], acc);
        acc = MFMA16(Ah1, wf[1 * 4 + nt], acc);
        acc = MFMA16(Aa0, wf[2 * 4 + nt], acc);
        acc = MFMA16(Aa1, wf[3 * 4 + nt], acc);
#pragma unroll
        for (int r = 0; r < 4; ++r) {
            long idx = (long)(n0 + 4 * g + r) * 64 + nt * 16 + c;
            float ho = h[idx];
            float hn = ho + fmaxf(acc[r], 0.f);
            h[idx] = hn;
            hb[idx] = f2b(hn);
        }
    }
}

// ---------------- fp32 scalar fallbacks (flag==0 only) ----------------
__global__ __launch_bounds__(256) void k_edges_sc(const float* h, float* agg,
                                                  const float* d2, const int* rowptr,
                                                  const int* eidx, const int* src,
                                                  const float* W1, const float* b1,
                                                  const float* W2, const float* b2,
                                                  const int* flag) {
    if (flag[0]) return;
    int node = blockIdx.x * 4 + (threadIdx.x >> 6);
    int j = threadIdx.x & 63;
    float hj = h[node * 64 + j];
    int e0 = rowptr[node], e1 = rowptr[node + 1];
    float acc = 0.f;
    float b1j = b1[j], b2j = b2[j];
    for (int t = e0; t < e1; ++t) {
        int e = eidx[t];
        int s = src[e];
        float hs = h[s * 64 + j];
        float dd = d2[e];
        float a = b1j;
#pragma unroll
        for (int k = 0; k < 64; ++k) a += bcastf(hs, k) * W1[k * 64 + j];
#pragma unroll
        for (int k = 0; k < 64; ++k) a += bcastf(hj, k) * W1[(64 + k) * 64 + j];
        a += dd * W1[128 * 64 + j];
        float hid = fmaxf(a, 0.f);
        float m = b2j;
#pragma unroll
        for (int k = 0; k < 64; ++k) m += bcastf(hid, k) * W2[k * 64 + j];
        acc += m;
    }
    agg[node * 64 + j] = acc;
}

__global__ __launch_bounds__(256) void k_node_sc(float* h, const float* agg,
                                                 const float* W3, const float* b3,
                                                 const int* flag) {
    if (flag[0]) return;
    int node = blockIdx.x * 4 + (threadIdx.x >> 6);
    int j = threadIdx.x & 63;
    float hj = h[node * 64 + j];
    float aj = agg[node * 64 + j];
    float u = b3[j];
#pragma unroll
    for (int k = 0; k < 64; ++k) u += bcastf(hj, k) * W3[k * 64 + j];
#pragma unroll
    for (int k = 0; k < 64; ++k) u += bcastf(aj, k) * W3[(64 + k) * 64 + j];
    h[node * 64 + j] = hj + fmaxf(u, 0.f);
}

// ---------------- pooling ----------------
__global__ __launch_bounds__(256) void k_count(const int* __restrict__ batch,
                                               float* __restrict__ cnt) {
    int i = blockIdx.x * 256 + threadIdx.x;
    if (i < NN) atomicAdd(&cnt[batch[i]], 1.f);
}

template<int BF16>
__device__ __forceinline__ void final_body(const float* h, const int* batch,
                                           const void* Wlin, const void* blin,
                                           float* pool) {
    int node = blockIdx.x * 4 + (threadIdx.x >> 6);
    int j = threadIdx.x & 63;
    int jj = j & 31;
    float v = fmaxf(h[node * 64 + j], 0.f);
    float acc = ldf<BF16>(blin, jj);
#pragma unroll
    for (int k = 0; k < 64; ++k)
        acc += bcastf(v, k) * ldf<BF16>(Wlin, k * 32 + jj);
    if (j < 32) atomicAdd(&pool[batch[node] * 32 + jj], acc);
}
__global__ __launch_bounds__(256) void k_final(const float* h, const int* batch,
                                               const void* Wlin, const void* blin,
                                               float* pool, const int* flag) {
    if (flag[0]) final_body<1>(h, batch, Wlin, blin, pool);
    else         final_body<0>(h, batch, Wlin, blin, pool);
}

__global__ __launch_bounds__(256) void k_out(const float* __restrict__ pool,
                                             const float* __restrict__ cnt,
                                             void* __restrict__ out,
                                             const int* __restrict__ flag) {
    int idx = blockIdx.x * 256 + threadIdx.x;
    if (idx >= 64 * 32) return;
    int g = idx >> 5;
    float c = fmaxf(cnt[g], 1.f);
    float v = pool[idx] / c;
    if (flag[0]) ((__hip_bfloat16*)out)[idx] = __float2bfloat16(v);
    else         ((float*)out)[idx] = v;
}

extern "C" void kernel_launch(void* const* d_in, const int* in_sizes, int n_in,
                              void* d_out, int out_size, void* d_ws, size_t ws_size,
                              hipStream_t stream) {
    const void* pos    = d_in[0];
    const int*  z      = (const int*)d_in[1];
    const int*  ei     = (const int*)d_in[2];
    const int*  batch  = (const int*)d_in[3];
    const void* emb    = d_in[4];
    const void* t1_Win = d_in[5];
    const u16*  t1_W1  = (const u16*)d_in[6];
    const u16*  t1_b1  = (const u16*)d_in[7];
    const u16*  t1_W2  = (const u16*)d_in[8];
    const u16*  t1_b2  = (const u16*)d_in[9];
    const u16*  t1_W3  = (const u16*)d_in[10];
    const u16*  t1_b3  = (const u16*)d_in[11];
    const void* t2_Win = d_in[12];
    const u16*  t2_W1  = (const u16*)d_in[13];
    const u16*  t2_b1  = (const u16*)d_in[14];
    const u16*  t2_W2  = (const u16*)d_in[15];
    const u16*  t2_b2  = (const u16*)d_in[16];
    const u16*  t2_W3  = (const u16*)d_in[17];
    const u16*  t2_b3  = (const u16*)d_in[18];
    const void* Wlin   = d_in[19];
    const void* blin   = d_in[20];

    const int* srcI = ei;
    const int* dstI = ei + EE;

    char* ws = (char*)d_ws;
    size_t off = 0;
    auto alloc = [&](size_t bytes) -> void* {
        void* p = ws + off;
        off += (bytes + 255) / 256 * 256;
        return p;
    };
    float* bufA   = (float*)alloc((size_t)NN * 64 * 4);
    float* bufB   = (float*)alloc((size_t)NN * 64 * 4);
    float* d2     = (float*)alloc((size_t)EE * 4);
    int*   rowptr = (int*)alloc((size_t)(NN + 1) * 4);
    int*   cursor = (int*)alloc((size_t)NN * 4);
    int*   eidx   = (int*)alloc((size_t)EE * 4);
    float* pool   = (float*)alloc(64 * 32 * 4);
    float* cnt    = (float*)alloc(64 * 4);
    int*   flag   = (int*)alloc(256);
    u16*   hb     = (u16*)alloc((size_t)NN * 64 * 2);
    void*  aggbuf = alloc((size_t)NN * 64 * 4);        // fp32 agg OR bf16 aggb
    int*   srcc   = (int*)alloc((size_t)EE * 4);
    float* d2c    = (float*)alloc((size_t)(EE + 16) * 4);
    u16*   Ws     = (u16*)alloc((size_t)8 * 20480 * 2);

    u16*   aggb = (u16*)aggbuf;
    float* agg  = (float*)aggbuf;

    k_detect<<<1, 64, 0, stream>>>(pos, flag);

    // embed + input proj (writes h fp32 + hb bf16)
    k_embed<<<NN * 64 / 256, 256, 0, stream>>>(pos, z, emb, bufB, flag);
    k_proj<<<NN / 4, 256, 0, stream>>>(bufB, bufA, hb, t1_Win, 0, flag);
    k_d2<<<(EE + 255) / 256, 256, 0, stream>>>(pos, srcI, dstI, d2, flag);

    // CSR by dst
    hipMemsetAsync(cursor, 0, (size_t)NN * 4, stream);
    k_deg<<<(EE + 255) / 256, 256, 0, stream>>>(dstI, cursor);
    k_scan<<<1, 1024, 0, stream>>>(cursor, rowptr);
    hipMemcpyAsync(cursor, rowptr, (size_t)NN * 4, hipMemcpyDeviceToDevice, stream);
    k_scatter<<<(EE + 255) / 256, 256, 0, stream>>>(dstI, cursor, eidx);
    k_reorder<<<(EE + 255) / 256, 256, 0, stream>>>(eidx, srcI, d2, srcc, d2c);

    // swizzle all 8 layers of W1/W2/W3 into MFMA frag order
    k_swz<<<8 * 20480 / 256, 256, 0, stream>>>(t1_W1, t1_W2, t1_W3,
                                               t2_W1, t2_W2, t2_W3, Ws);

    const int NB = NN / 4;           // 25000 blocks (wave per node)
    const int NTB = (NN / 16 + 3) / 4 + 1;  // node-tile blocks: 1563

    // transformer 1 (h in bufA)
    for (int l = 0; l < 4; ++l) {
        const u16* Wsl = Ws + (size_t)l * 20480;
        k_edges_mfma<<<NB, 256, 0, stream>>>(hb, aggb, d2c, rowptr, srcc, Wsl,
                                             t1_W1 + (size_t)l * 129 * 64,
                                             t1_b1 + (size_t)l * 64,
                                             t1_b2 + (size_t)l * 64, flag);
        k_edges_sc<<<NB, 256, 0, stream>>>(bufA, agg, d2, rowptr, eidx, srcI,
                                           (const float*)d_in[6] + (size_t)l * 129 * 64,
                                           (const float*)d_in[7] + (size_t)l * 64,
                                           (const float*)d_in[8] + (size_t)l * 64 * 64,
                                           (const float*)d_in[9] + (size_t)l * 64, flag);
        k_node_mfma<<<NTB, 256, 0, stream>>>(bufA, hb, aggb, Wsl,
                                             t1_b3 + (size_t)l * 64, flag);
        k_node_sc<<<NB, 256, 0, stream>>>(bufA, agg,
                                          (const float*)d_in[10] + (size_t)l * 128 * 64,
                                          (const float*)d_in[11] + (size_t)l * 64, flag);
    }

    // transformer 2 (h in bufB)
    k_proj<<<NB, 256, 0, stream>>>(bufA, bufB, hb, t2_Win, 1, flag);
    for (int l = 0; l < 4; ++l) {
        const u16* Wsl = Ws + (size_t)(4 + l) * 20480;
        k_edges_mfma<<<NB, 256, 0, stream>>>(hb, aggb, d2c, rowptr, srcc, Wsl,
                                             t2_W1 + (size_t)l * 129 * 64,
                                             t2_b1 + (size_t)l * 64,
                                             t2_b2 + (size_t)l * 64, flag);
        k_edges_sc<<<NB, 256, 0, stream>>>(bufB, agg, d2, rowptr, eidx, srcI,
                                           (const float*)d_in[13] + (size_t)l * 129 * 64,
                                           (const float*)d_in[14] + (size_t)l * 64,
                                           (const float*)d_in[15] + (size_t)l * 64 * 64,
                                           (const float*)d_in[16] + (size_t)l * 64, flag);
        k_node_mfma<<<NTB, 256, 0, stream>>>(bufB, hb, aggb, Wsl,
                                             t2_b3 + (size_t)l * 64, flag);
        k_node_sc<<<NB, 256, 0, stream>>>(bufB, agg,
                                          (const float*)d_in[17] + (size_t)l * 128 * 64,
                                          (const float*)d_in[18] + (size_t)l * 64, flag);
    }

    // pooled mean
    hipMemsetAsync(pool, 0, 64 * 32 * 4, stream);
    hipMemsetAsync(cnt, 0, 64 * 4, stream);
    k_count<<<(NN + 255) / 256, 256, 0, stream>>>(batch, cnt);
    k_final<<<NB, 256, 0, stream>>>(bufB, batch, Wlin, blin, pool, flag);
    k_out<<<8, 256, 0, stream>>>(pool, cnt, d_out, flag);
}

// Round 4
// 3118.329 us; speedup vs baseline: 3.0370x; 3.0370x over previous
//
#include <hip/hip_runtime.h>
#include <hip/hip_bf16.h>

typedef unsigned short u16;
typedef unsigned int   u32;
typedef short bf16x8 __attribute__((ext_vector_type(8)));
typedef float f32x4  __attribute__((ext_vector_type(4)));

#define NN 100000
#define EE 800000

#define MFMA16(a,b,c) __builtin_amdgcn_mfma_f32_16x16x32_bf16(a,b,c,0,0,0)

__device__ __forceinline__ float b2f(u16 u) {
    u32 x = ((u32)u) << 16;
    return __uint_as_float(x);
}
__device__ __forceinline__ u16 f2b(float f) {
    __hip_bfloat16 h = __float2bfloat16(f);
    return *reinterpret_cast<u16*>(&h);
}
__device__ __forceinline__ void splt(float v, u16& hi, u16& lo) {
    hi = f2b(v);
    lo = f2b(v - b2f(hi));
}
__device__ __forceinline__ float bcastf(float v, int l) {
    return __uint_as_float(__builtin_amdgcn_readlane(__float_as_uint(v), l));
}

// ---------------- embed: x[N,64] = [pos(3)|emb[z](61)] as bf16 hi/lo ----------------
__global__ __launch_bounds__(256) void k_embed(const float* __restrict__ pos,
                                               const int* __restrict__ z,
                                               const float* __restrict__ emb,
                                               u16* __restrict__ xh,
                                               u16* __restrict__ xl) {
    int gid = blockIdx.x * 256 + threadIdx.x;   // N*64 exactly
    int i = gid >> 6, f = gid & 63;
    float v = (f < 3) ? pos[i * 3 + f] : emb[(long)z[i] * 61 + (f - 3)];
    u16 hi, lo; splt(v, hi, lo);
    xh[gid] = hi; xl[gid] = lo;
}

// ---------------- CSR build ----------------
__global__ __launch_bounds__(256) void k_deg(const int* __restrict__ dst,
                                             int* __restrict__ deg) {
    int e = blockIdx.x * 256 + threadIdx.x;
    if (e < EE) atomicAdd(&deg[dst[e]], 1);
}

__global__ __launch_bounds__(1024) void k_scan(const int* __restrict__ deg,
                                               int* __restrict__ rowptr) {
    __shared__ int s[1024];
    int carry = 0;
    for (int base = 0; base < NN; base += 1024) {
        int i = base + (int)threadIdx.x;
        int v = (i < NN) ? deg[i] : 0;
        s[threadIdx.x] = v;
        __syncthreads();
        for (int off = 1; off < 1024; off <<= 1) {
            int t = (threadIdx.x >= (unsigned)off) ? s[threadIdx.x - off] : 0;
            __syncthreads();
            s[threadIdx.x] += t;
            __syncthreads();
        }
        int incl = s[threadIdx.x];
        if (i < NN) rowptr[i] = carry + incl - v;
        carry += s[1023];
        __syncthreads();
    }
    if (threadIdx.x == 0) rowptr[NN] = carry;
}

// scatter edges into CSR slots; computes d2 inline (order within a segment is
// irrelevant: segment-sum is commutative, fp32 rounding diffs only)
__global__ __launch_bounds__(256) void k_scatter(const int* __restrict__ src,
                                                 const int* __restrict__ dst,
                                                 const float* __restrict__ pos,
                                                 int* __restrict__ cursor,
                                                 int* __restrict__ srcc,
                                                 float* __restrict__ d2c) {
    int e = blockIdx.x * 256 + threadIdx.x;
    if (e >= EE) return;
    int d = dst[e], s = src[e];
    int p = atomicAdd(&cursor[d], 1);
    srcc[p] = s;
    float dx = pos[s * 3 + 0] - pos[d * 3 + 0];
    float dy = pos[s * 3 + 1] - pos[d * 3 + 1];
    float dz = pos[s * 3 + 2] - pos[d * 3 + 2];
    d2c[p] = dx * dx + dy * dy + dz * dz;
}

// ---------------- weight swizzle (fp32 -> bf16 hi/lo B-frags) ----------------
// Layer block (per L in 0..7), in u16 elems: [W1hi 8192][W2hi 4096][W3hi 8192]
// then lo copies at +20480. Frag elem j of (f,lane):
//   row = (f>>2)*32 + (lane>>4)*8 + j , col = (f&3)*16 + (lane&15)
// WsB: [Win1 hi 4096][Win1 lo 4096][Win2 hi 4096][Win2 lo 4096]
__global__ __launch_bounds__(256) void k_swz(const float* t1W1, const float* t1W2, const float* t1W3,
                                             const float* t2W1, const float* t2W2, const float* t2W3,
                                             const float* t1Win, const float* t2Win,
                                             u16* __restrict__ WsA, u16* __restrict__ WsB) {
    int gid = blockIdx.x * 256 + threadIdx.x;   // 172032 exactly
    if (gid < 163840) {
        int L = gid / 20480;
        int r = gid % 20480;
        const float* W1 = (L < 4 ? t1W1 : t2W1) + (size_t)(L & 3) * 129 * 64;
        const float* W2 = (L < 4 ? t1W2 : t2W2) + (size_t)(L & 3) * 64 * 64;
        const float* W3 = (L < 4 ? t1W3 : t2W3) + (size_t)(L & 3) * 128 * 64;
        float w;
        int rr, f, e, lane, j, row, col;
        if (r < 8192) { rr = r; f = rr >> 9; e = rr & 511; lane = e >> 3; j = e & 7;
            row = (f >> 2) * 32 + (lane >> 4) * 8 + j; col = (f & 3) * 16 + (lane & 15);
            w = W1[row * 64 + col];
        } else if (r < 12288) { rr = r - 8192; f = rr >> 9; e = rr & 511; lane = e >> 3; j = e & 7;
            row = (f >> 2) * 32 + (lane >> 4) * 8 + j; col = (f & 3) * 16 + (lane & 15);
            w = W2[row * 64 + col];
        } else { rr = r - 12288; f = rr >> 9; e = rr & 511; lane = e >> 3; j = e & 7;
            row = (f >> 2) * 32 + (lane >> 4) * 8 + j; col = (f & 3) * 16 + (lane & 15);
            w = W3[row * 64 + col];
        }
        u16 hi, lo; splt(w, hi, lo);
        WsA[(size_t)L * 40960 + r] = hi;
        WsA[(size_t)L * 40960 + 20480 + r] = lo;
    } else {
        int t = gid - 163840;               // 0..8191
        int sel = (t < 4096) ? 0 : 1;
        int rr = t & 4095;
        const float* Win = sel ? t2Win : t1Win;
        int f = rr >> 9, e = rr & 511, lane = e >> 3, j = e & 7;
        int row = (f >> 2) * 32 + (lane >> 4) * 8 + j;
        int col = (f & 3) * 16 + (lane & 15);
        float w = Win[row * 64 + col];
        u16 hi, lo; splt(w, hi, lo);
        WsB[sel * 8192 + rr] = hi;
        WsB[sel * 8192 + 4096 + rr] = lo;
    }
}

// ---------------- dense proj: h = x @ Win (16 nodes/wave, bf16x2 split) -------
__global__ __launch_bounds__(256) void k_proj_mfma(const u16* __restrict__ xh,
                                                   const u16* __restrict__ xl,
                                                   const u16* __restrict__ WinS,
                                                   float* __restrict__ h,
                                                   u16* __restrict__ hbh,
                                                   u16* __restrict__ hbl) {
    int tile = blockIdx.x * 4 + (threadIdx.x >> 6);
    if (tile >= NN / 16) return;
    int lane = threadIdx.x & 63, c = lane & 15, g = lane >> 4;
    int n0 = tile * 16, nr = n0 + c;
    const bf16x8* Wh = (const bf16x8*)WinS;
    const bf16x8* Wl = (const bf16x8*)(WinS + 4096);
    const bf16x8* ph = (const bf16x8*)(xh + (long)nr * 64);
    const bf16x8* pl = (const bf16x8*)(xl + (long)nr * 64);
    bf16x8 A0h = ph[g], A1h = ph[g + 4], A0l = pl[g], A1l = pl[g + 4];
#pragma unroll
    for (int nt = 0; nt < 4; ++nt) {
        f32x4 acc = {0.f, 0.f, 0.f, 0.f};
        acc = MFMA16(A0h, Wh[nt * 64 + lane], acc);
        acc = MFMA16(A1h, Wh[(4 + nt) * 64 + lane], acc);
        acc = MFMA16(A0l, Wh[nt * 64 + lane], acc);
        acc = MFMA16(A1l, Wh[(4 + nt) * 64 + lane], acc);
        acc = MFMA16(A0h, Wl[nt * 64 + lane], acc);
        acc = MFMA16(A1h, Wl[(4 + nt) * 64 + lane], acc);
#pragma unroll
        for (int r = 0; r < 4; ++r) {
            long idx = (long)(n0 + 4 * g + r) * 64 + nt * 16 + c;
            h[idx] = acc[r];
            u16 hi, lo; splt(acc[r], hi, lo);
            hbh[idx] = hi; hbl[idx] = lo;
        }
    }
}

// relu(h) -> bf16 hi/lo mirrors (for the t2 input projection)
__global__ __launch_bounds__(256) void k_relu_split(const float* __restrict__ h,
                                                    u16* __restrict__ rh,
                                                    u16* __restrict__ rl) {
    int gid = blockIdx.x * 256 + threadIdx.x;
    float v = fmaxf(h[gid], 0.f);
    u16 hi, lo; splt(v, hi, lo);
    rh[gid] = hi; rl[gid] = lo;
}

// ---------------- dst-half of GEMM1 + b1, dense 16 nodes/wave ----------------
__global__ __launch_bounds__(256) void k_dsthalf(const u16* __restrict__ hbh,
                                                 const u16* __restrict__ hbl,
                                                 const u16* __restrict__ Wsl,
                                                 const float* __restrict__ b1,
                                                 float* __restrict__ accb) {
    int tile = blockIdx.x * 4 + (threadIdx.x >> 6);
    if (tile >= NN / 16) return;
    int lane = threadIdx.x & 63, c = lane & 15, g = lane >> 4;
    int n0 = tile * 16, nr = n0 + c;
    const bf16x8* W1h = (const bf16x8*)Wsl;
    const bf16x8* W1l = (const bf16x8*)(Wsl + 20480);
    const bf16x8* ph = (const bf16x8*)(hbh + (long)nr * 64);
    const bf16x8* pl = (const bf16x8*)(hbl + (long)nr * 64);
    bf16x8 A0h = ph[g], A1h = ph[g + 4], A0l = pl[g], A1l = pl[g + 4];
#pragma unroll
    for (int nt = 0; nt < 4; ++nt) {
        float bv = b1[nt * 16 + c];
        f32x4 acc = {bv, bv, bv, bv};
        acc = MFMA16(A0h, W1h[(8 + nt) * 64 + lane], acc);
        acc = MFMA16(A1h, W1h[(12 + nt) * 64 + lane], acc);
        acc = MFMA16(A0l, W1h[(8 + nt) * 64 + lane], acc);
        acc = MFMA16(A1l, W1h[(12 + nt) * 64 + lane], acc);
        acc = MFMA16(A0h, W1l[(8 + nt) * 64 + lane], acc);
        acc = MFMA16(A1h, W1l[(12 + nt) * 64 + lane], acc);
#pragma unroll
        for (int r = 0; r < 4; ++r)
            accb[(long)(n0 + 4 * g + r) * 64 + nt * 16 + c] = acc[r];
    }
}

// ---------------- edge MLP + aggregate: one wave per dst node ----------------
__global__ __launch_bounds__(256) void k_edges_mfma(const u16* __restrict__ hbh,
                                                    const u16* __restrict__ hbl,
                                                    u16* __restrict__ aggh,
                                                    u16* __restrict__ aggl,
                                                    const float* __restrict__ d2c,
                                                    const int* __restrict__ rowptr,
                                                    const int* __restrict__ srcc,
                                                    const u16* __restrict__ Wsl,
                                                    const float* __restrict__ W1f,
                                                    const float* __restrict__ accb,
                                                    const float* __restrict__ b2) {
    __shared__ u16 h1h[4][16 * 72];
    __shared__ u16 h1l[4][16 * 72];
    int w = threadIdx.x >> 6, lane = threadIdx.x & 63;
    int node = blockIdx.x * 4 + w;
    int c = lane & 15, g = lane >> 4;
    u16* hlh = h1h[w];
    u16* hll = h1l[w];

    const bf16x8* W1H = (const bf16x8*)Wsl;
    const bf16x8* W2H = (const bf16x8*)(Wsl + 8192);
    const bf16x8* W1L = (const bf16x8*)(Wsl + 20480);
    const bf16x8* W2L = (const bf16x8*)(Wsl + 20480 + 8192);

    // stationary frags (src-half of W1, all of W2), hi+lo
    bf16x8 w1h[2][4], w1l[2][4], w2h[2][4], w2l[2][4];
#pragma unroll
    for (int ks = 0; ks < 2; ++ks)
#pragma unroll
        for (int nt = 0; nt < 4; ++nt) {
            w1h[ks][nt] = W1H[(ks * 4 + nt) * 64 + lane];
            w1l[ks][nt] = W1L[(ks * 4 + nt) * 64 + lane];
            w2h[ks][nt] = W2H[(ks * 4 + nt) * 64 + lane];
            w2l[ks][nt] = W2L[(ks * 4 + nt) * 64 + lane];
        }
    float base_c[4], wdc[4];
#pragma unroll
    for (int nt = 0; nt < 4; ++nt) {
        base_c[nt] = accb[(long)node * 64 + nt * 16 + c];  // dst-half + b1
        wdc[nt] = W1f[128 * 64 + nt * 16 + c];             // d2 weight row
    }
    float b2c = b2[lane];

    int e0 = rowptr[node], e1 = rowptr[node + 1];
    f32x4 z = {0.f, 0.f, 0.f, 0.f};
    f32x4 acc2[4] = {z, z, z, z};

    for (int te = e0; te < e1; te += 16) {
        int t = te + c;
        if (t > e1 - 1) t = e1 - 1;
        int s = srcc[t];
        const bf16x8* sph = (const bf16x8*)(hbh + (long)s * 64);
        const bf16x8* spl = (const bf16x8*)(hbl + (long)s * 64);
        bf16x8 A0h = sph[g], A1h = sph[g + 4];
        bf16x8 A0l = spl[g], A1l = spl[g + 4];
        float dq[4];
#pragma unroll
        for (int r = 0; r < 4; ++r) dq[r] = d2c[te + 4 * g + r];
        int rem = e1 - te;
        f32x4 a1[4];
#pragma unroll
        for (int nt = 0; nt < 4; ++nt) {
            f32x4 ci;
#pragma unroll
            for (int r = 0; r < 4; ++r) ci[r] = base_c[nt] + dq[r] * wdc[nt];
            ci = MFMA16(A0h, w1h[0][nt], ci);
            ci = MFMA16(A1h, w1h[1][nt], ci);
            ci = MFMA16(A0l, w1h[0][nt], ci);
            ci = MFMA16(A1l, w1h[1][nt], ci);
            ci = MFMA16(A0h, w1l[0][nt], ci);
            ci = MFMA16(A1h, w1l[1][nt], ci);
            a1[nt] = ci;
        }
        // relu + pad-mask, C-layout -> row-major LDS [edge][72], hi/lo
#pragma unroll
        for (int nt = 0; nt < 4; ++nt)
#pragma unroll
            for (int r = 0; r < 4; ++r) {
                int m = 4 * g + r;
                float v = (m < rem) ? fmaxf(a1[nt][r], 0.f) : 0.f;
                u16 hi, lo; splt(v, hi, lo);
                hlh[m * 72 + nt * 16 + c] = hi;
                hll[m * 72 + nt * 16 + c] = lo;
            }
        bf16x8 F0h = *(const bf16x8*)(hlh + c * 72 + g * 8);
        bf16x8 F1h = *(const bf16x8*)(hlh + c * 72 + 32 + g * 8);
        bf16x8 F0l = *(const bf16x8*)(hll + c * 72 + g * 8);
        bf16x8 F1l = *(const bf16x8*)(hll + c * 72 + 32 + g * 8);
#pragma unroll
        for (int nt = 0; nt < 4; ++nt) {
            acc2[nt] = MFMA16(F0h, w2h[0][nt], acc2[nt]);
            acc2[nt] = MFMA16(F1h, w2h[1][nt], acc2[nt]);
            acc2[nt] = MFMA16(F0l, w2h[0][nt], acc2[nt]);
            acc2[nt] = MFMA16(F1l, w2h[1][nt], acc2[nt]);
            acc2[nt] = MFMA16(F0h, w2l[0][nt], acc2[nt]);
            acc2[nt] = MFMA16(F1h, w2l[1][nt], acc2[nt]);
        }
    }

    float deg = (float)(e1 - e0);
    float sv[4];
#pragma unroll
    for (int nt = 0; nt < 4; ++nt) {
        float s = acc2[nt][0] + acc2[nt][1] + acc2[nt][2] + acc2[nt][3];
        s += __shfl_xor(s, 16);
        s += __shfl_xor(s, 32);
        sv[nt] = s;
    }
    float v = sv[0];
    v = (g == 1) ? sv[1] : v;
    v = (g == 2) ? sv[2] : v;
    v = (g == 3) ? sv[3] : v;
    v += deg * b2c;
    u16 hi, lo; splt(v, hi, lo);
    aggh[(long)node * 64 + lane] = hi;
    aggl[(long)node * 64 + lane] = lo;
}

// ---------------- node update: h += relu([h,agg]@W3 + b3), 16 nodes/wave -----
__global__ __launch_bounds__(256) void k_node_mfma(float* __restrict__ h,
                                                   u16* __restrict__ hbh,
                                                   u16* __restrict__ hbl,
                                                   const u16* __restrict__ aggh,
                                                   const u16* __restrict__ aggl,
                                                   const u16* __restrict__ Wsl,
                                                   const float* __restrict__ b3) {
    int tile = blockIdx.x * 4 + (threadIdx.x >> 6);
    if (tile >= NN / 16) return;
    int lane = threadIdx.x & 63, c = lane & 15, g = lane >> 4;
    int n0 = tile * 16, nr = n0 + c;
    const bf16x8* W3H = (const bf16x8*)(Wsl + 12288);
    const bf16x8* W3L = (const bf16x8*)(Wsl + 20480 + 12288);
    const bf16x8* phh = (const bf16x8*)(hbh + (long)nr * 64);
    const bf16x8* phl = (const bf16x8*)(hbl + (long)nr * 64);
    const bf16x8* pah = (const bf16x8*)(aggh + (long)nr * 64);
    const bf16x8* pal = (const bf16x8*)(aggl + (long)nr * 64);
    bf16x8 Ah0h = phh[g], Ah1h = phh[g + 4], Ah0l = phl[g], Ah1l = phl[g + 4];
    bf16x8 Aa0h = pah[g], Aa1h = pah[g + 4], Aa0l = pal[g], Aa1l = pal[g + 4];
#pragma unroll
    for (int nt = 0; nt < 4; ++nt) {
        float bv = b3[nt * 16 + c];
        f32x4 acc = {bv, bv, bv, bv};
        acc = MFMA16(Ah0h, W3H[nt * 64 + lane], acc);
        acc = MFMA16(Ah1h, W3H[(4 + nt) * 64 + lane], acc);
        acc = MFMA16(Aa0h, W3H[(8 + nt) * 64 + lane], acc);
        acc = MFMA16(Aa1h, W3H[(12 + nt) * 64 + lane], acc);
        acc = MFMA16(Ah0l, W3H[nt * 64 + lane], acc);
        acc = MFMA16(Ah1l, W3H[(4 + nt) * 64 + lane], acc);
        acc = MFMA16(Aa0l, W3H[(8 + nt) * 64 + lane], acc);
        acc = MFMA16(Aa1l, W3H[(12 + nt) * 64 + lane], acc);
        acc = MFMA16(Ah0h, W3L[nt * 64 + lane], acc);
        acc = MFMA16(Ah1h, W3L[(4 + nt) * 64 + lane], acc);
        acc = MFMA16(Aa0h, W3L[(8 + nt) * 64 + lane], acc);
        acc = MFMA16(Aa1h, W3L[(12 + nt) * 64 + lane], acc);
#pragma unroll
        for (int r = 0; r < 4; ++r) {
            long idx = (long)(n0 + 4 * g + r) * 64 + nt * 16 + c;
            float ho = h[idx];
            float hn = ho + fmaxf(acc[r], 0.f);
            h[idx] = hn;
            u16 hi, lo; splt(hn, hi, lo);
            hbh[idx] = hi; hbl[idx] = lo;
        }
    }
}

// ---------------- pooling (fp32, proven path) ----------------
__global__ __launch_bounds__(256) void k_count(const int* __restrict__ batch,
                                               float* __restrict__ cnt) {
    int i = blockIdx.x * 256 + threadIdx.x;
    if (i < NN) atomicAdd(&cnt[batch[i]], 1.f);
}

__global__ __launch_bounds__(256) void k_final(const float* __restrict__ h,
                                               const int* __restrict__ batch,
                                               const float* __restrict__ Wlin,
                                               const float* __restrict__ blin,
                                               float* __restrict__ pool) {
    int node = blockIdx.x * 4 + (threadIdx.x >> 6);
    int j = threadIdx.x & 63;
    int jj = j & 31;
    float v = fmaxf(h[node * 64 + j], 0.f);
    float acc = blin[jj];
#pragma unroll
    for (int k = 0; k < 64; ++k)
        acc += bcastf(v, k) * Wlin[k * 32 + jj];
    if (j < 32) atomicAdd(&pool[batch[node] * 32 + jj], acc);
}

__global__ __launch_bounds__(256) void k_out(const float* __restrict__ pool,
                                             const float* __restrict__ cnt,
                                             float* __restrict__ out) {
    int idx = blockIdx.x * 256 + threadIdx.x;
    if (idx >= 64 * 32) return;
    int g = idx >> 5;
    float c = fmaxf(cnt[g], 1.f);
    out[idx] = pool[idx] / c;
}

extern "C" void kernel_launch(void* const* d_in, const int* in_sizes, int n_in,
                              void* d_out, int out_size, void* d_ws, size_t ws_size,
                              hipStream_t stream) {
    const float* pos    = (const float*)d_in[0];
    const int*   z      = (const int*)d_in[1];
    const int*   ei     = (const int*)d_in[2];
    const int*   batch  = (const int*)d_in[3];
    const float* emb    = (const float*)d_in[4];
    const float* t1_Win = (const float*)d_in[5];
    const float* t1_W1  = (const float*)d_in[6];
    const float* t1_b1  = (const float*)d_in[7];
    const float* t1_W2  = (const float*)d_in[8];
    const float* t1_b2  = (const float*)d_in[9];
    const float* t1_W3  = (const float*)d_in[10];
    const float* t1_b3  = (const float*)d_in[11];
    const float* t2_Win = (const float*)d_in[12];
    const float* t2_W1  = (const float*)d_in[13];
    const float* t2_b1  = (const float*)d_in[14];
    const float* t2_W2  = (const float*)d_in[15];
    const float* t2_b2  = (const float*)d_in[16];
    const float* t2_W3  = (const float*)d_in[17];
    const float* t2_b3  = (const float*)d_in[18];
    const float* Wlin   = (const float*)d_in[19];
    const float* blin   = (const float*)d_in[20];

    const int* srcI = ei;
    const int* dstI = ei + EE;

    char* ws = (char*)d_ws;
    size_t off = 0;
    auto alloc = [&](size_t bytes) -> void* {
        void* p = ws + off;
        off += (bytes + 255) / 256 * 256;
        return p;
    };
    float* bufH   = (float*)alloc((size_t)NN * 64 * 4);   // h master (fp32)
    float* accb   = (float*)alloc((size_t)NN * 64 * 4);   // dst-half+b1; aliases x/relu mirrors
    u16*   hbh    = (u16*)alloc((size_t)NN * 64 * 2);
    u16*   hbl    = (u16*)alloc((size_t)NN * 64 * 2);
    u16*   aggh   = (u16*)alloc((size_t)NN * 64 * 2);
    u16*   aggl   = (u16*)alloc((size_t)NN * 64 * 2);
    int*   rowptr = (int*)alloc((size_t)(NN + 1) * 4);
    int*   cursor = (int*)alloc((size_t)NN * 4);
    int*   srcc   = (int*)alloc((size_t)EE * 4);
    float* d2c    = (float*)alloc((size_t)(EE + 16) * 4);
    float* pool   = (float*)alloc(64 * 32 * 4);
    float* cnt    = (float*)alloc(64 * 4);
    u16*   WsA    = (u16*)alloc((size_t)8 * 40960 * 2);
    u16*   WsB    = (u16*)alloc((size_t)16384 * 2);

    // x / relu(h) bf16 mirrors live in the accb region (disjoint lifetimes)
    u16* xh = (u16*)accb;
    u16* xl = (u16*)accb + (size_t)NN * 64;

    const int NTB = (NN / 16 + 3) / 4 + 1;   // 1563 blocks of 4 node-tiles
    const int NB  = NN / 4;                  // 25000 blocks (wave per node)

    // prologue: embed + CSR + weight swizzle
    k_embed<<<NN * 64 / 256, 256, 0, stream>>>(pos, z, emb, xh, xl);
    hipMemsetAsync(cursor, 0, (size_t)NN * 4, stream);
    k_deg<<<(EE + 255) / 256, 256, 0, stream>>>(dstI, cursor);
    k_scan<<<1, 1024, 0, stream>>>(cursor, rowptr);
    hipMemcpyAsync(cursor, rowptr, (size_t)NN * 4, hipMemcpyDeviceToDevice, stream);
    k_scatter<<<(EE + 255) / 256, 256, 0, stream>>>(srcI, dstI, pos, cursor, srcc, d2c);
    k_swz<<<172032 / 256, 256, 0, stream>>>(t1_W1, t1_W2, t1_W3, t2_W1, t2_W2, t2_W3,
                                            t1_Win, t2_Win, WsA, WsB);

    // transformer 1
    k_proj_mfma<<<NTB, 256, 0, stream>>>(xh, xl, WsB, bufH, hbh, hbl);
    for (int l = 0; l < 4; ++l) {
        const u16* Wsl = WsA + (size_t)l * 40960;
        k_dsthalf<<<NTB, 256, 0, stream>>>(hbh, hbl, Wsl, t1_b1 + (size_t)l * 64, accb);
        k_edges_mfma<<<NB, 256, 0, stream>>>(hbh, hbl, aggh, aggl, d2c, rowptr, srcc,
                                             Wsl, t1_W1 + (size_t)l * 129 * 64, accb,
                                             t1_b2 + (size_t)l * 64);
        k_node_mfma<<<NTB, 256, 0, stream>>>(bufH, hbh, hbl, aggh, aggl, Wsl,
                                             t1_b3 + (size_t)l * 64);
    }

    // transformer 2
    k_relu_split<<<NN * 64 / 256, 256, 0, stream>>>(bufH, xh, xl);
    k_proj_mfma<<<NTB, 256, 0, stream>>>(xh, xl, WsB + 8192, bufH, hbh, hbl);
    for (int l = 0; l < 4; ++l) {
        const u16* Wsl = WsA + (size_t)(4 + l) * 40960;
        k_dsthalf<<<NTB, 256, 0, stream>>>(hbh, hbl, Wsl, t2_b1 + (size_t)l * 64, accb);
        k_edges_mfma<<<NB, 256, 0, stream>>>(hbh, hbl, aggh, aggl, d2c, rowptr, srcc,
                                             Wsl, t2_W1 + (size_t)l * 129 * 64, accb,
                                             t2_b2 + (size_t)l * 64);
        k_node_mfma<<<NTB, 256, 0, stream>>>(bufH, hbh, hbl, aggh, aggl, Wsl,
                                             t2_b3 + (size_t)l * 64);
    }

    // pooled mean
    hipMemsetAsync(pool, 0, 64 * 32 * 4, stream);
    hipMemsetAsync(cnt, 0, 64 * 4, stream);
    k_count<<<(NN + 255) / 256, 256, 0, stream>>>(batch, cnt);
    k_final<<<NB, 256, 0, stream>>>(bufH, batch, Wlin, blin, pool);
    k_out<<<8, 256, 0, stream>>>(pool, cnt, (float*)d_out);
}

// Round 5
// 2349.554 us; speedup vs baseline: 4.0307x; 1.3272x over previous
//
#include <hip/hip_runtime.h>
#include <hip/hip_bf16.h>

typedef unsigned short u16;
typedef unsigned int   u32;
typedef short bf16x8 __attribute__((ext_vector_type(8)));
typedef float f32x4  __attribute__((ext_vector_type(4)));

#define NN 100000
#define EE 800000

#define MFMA16(a,b,c) __builtin_amdgcn_mfma_f32_16x16x32_bf16(a,b,c,0,0,0)

__device__ __forceinline__ float b2f(u16 u) {
    u32 x = ((u32)u) << 16;
    return __uint_as_float(x);
}
__device__ __forceinline__ u16 f2b(float f) {
    __hip_bfloat16 h = __float2bfloat16(f);
    return *reinterpret_cast<u16*>(&h);
}
__device__ __forceinline__ void splt(float v, u16& hi, u16& lo) {
    hi = f2b(v);
    lo = f2b(v - b2f(hi));
}

// ---------------- embed: x[N,64] = [pos(3)|emb[z](61)] as bf16 hi/lo ----------------
__global__ __launch_bounds__(256) void k_embed(const float* __restrict__ pos,
                                               const int* __restrict__ z,
                                               const float* __restrict__ emb,
                                               u16* __restrict__ xh,
                                               u16* __restrict__ xl) {
    int gid = blockIdx.x * 256 + threadIdx.x;   // N*64 exactly
    int i = gid >> 6, f = gid & 63;
    float v = (f < 3) ? pos[i * 3 + f] : emb[(long)z[i] * 61 + (f - 3)];
    u16 hi, lo; splt(v, hi, lo);
    xh[gid] = hi; xl[gid] = lo;
}

// ---------------- CSR build ----------------
__global__ __launch_bounds__(256) void k_deg(const int* __restrict__ dst,
                                             int* __restrict__ deg) {
    int e = blockIdx.x * 256 + threadIdx.x;
    if (e < EE) atomicAdd(&deg[dst[e]], 1);
}

__global__ __launch_bounds__(1024) void k_scan(const int* __restrict__ deg,
                                               int* __restrict__ rowptr) {
    __shared__ int s[1024];
    int carry = 0;
    for (int base = 0; base < NN; base += 1024) {
        int i = base + (int)threadIdx.x;
        int v = (i < NN) ? deg[i] : 0;
        s[threadIdx.x] = v;
        __syncthreads();
        for (int off = 1; off < 1024; off <<= 1) {
            int t = (threadIdx.x >= (unsigned)off) ? s[threadIdx.x - off] : 0;
            __syncthreads();
            s[threadIdx.x] += t;
            __syncthreads();
        }
        int incl = s[threadIdx.x];
        if (i < NN) rowptr[i] = carry + incl - v;
        carry += s[1023];
        __syncthreads();
    }
    if (threadIdx.x == 0) rowptr[NN] = carry;
}

// scatter edges into CSR slots; computes d2 inline
__global__ __launch_bounds__(256) void k_scatter(const int* __restrict__ src,
                                                 const int* __restrict__ dst,
                                                 const float* __restrict__ pos,
                                                 int* __restrict__ cursor,
                                                 int* __restrict__ srcc,
                                                 float* __restrict__ d2c) {
    int e = blockIdx.x * 256 + threadIdx.x;
    if (e >= EE) return;
    int d = dst[e], s = src[e];
    int p = atomicAdd(&cursor[d], 1);
    srcc[p] = s;
    float dx = pos[s * 3 + 0] - pos[d * 3 + 0];
    float dy = pos[s * 3 + 1] - pos[d * 3 + 1];
    float dz = pos[s * 3 + 2] - pos[d * 3 + 2];
    d2c[p] = dx * dx + dy * dy + dz * dz;
}

// ---------------- weight swizzle (fp32 -> bf16 hi/lo B-frags) ----------------
__global__ __launch_bounds__(256) void k_swz(const float* t1W1, const float* t1W2, const float* t1W3,
                                             const float* t2W1, const float* t2W2, const float* t2W3,
                                             const float* t1Win, const float* t2Win,
                                             u16* __restrict__ WsA, u16* __restrict__ WsB) {
    int gid = blockIdx.x * 256 + threadIdx.x;   // 172032 exactly
    if (gid < 163840) {
        int L = gid / 20480;
        int r = gid % 20480;
        const float* W1 = (L < 4 ? t1W1 : t2W1) + (size_t)(L & 3) * 129 * 64;
        const float* W2 = (L < 4 ? t1W2 : t2W2) + (size_t)(L & 3) * 64 * 64;
        const float* W3 = (L < 4 ? t1W3 : t2W3) + (size_t)(L & 3) * 128 * 64;
        float w;
        int rr, f, e, lane, j, row, col;
        if (r < 8192) { rr = r; f = rr >> 9; e = rr & 511; lane = e >> 3; j = e & 7;
            row = (f >> 2) * 32 + (lane >> 4) * 8 + j; col = (f & 3) * 16 + (lane & 15);
            w = W1[row * 64 + col];
        } else if (r < 12288) { rr = r - 8192; f = rr >> 9; e = rr & 511; lane = e >> 3; j = e & 7;
            row = (f >> 2) * 32 + (lane >> 4) * 8 + j; col = (f & 3) * 16 + (lane & 15);
            w = W2[row * 64 + col];
        } else { rr = r - 12288; f = rr >> 9; e = rr & 511; lane = e >> 3; j = e & 7;
            row = (f >> 2) * 32 + (lane >> 4) * 8 + j; col = (f & 3) * 16 + (lane & 15);
            w = W3[row * 64 + col];
        }
        u16 hi, lo; splt(w, hi, lo);
        WsA[(size_t)L * 40960 + r] = hi;
        WsA[(size_t)L * 40960 + 20480 + r] = lo;
    } else {
        int t = gid - 163840;               // 0..8191
        int sel = (t < 4096) ? 0 : 1;
        int rr = t & 4095;
        const float* Win = sel ? t2Win : t1Win;
        int f = rr >> 9, e = rr & 511, lane = e >> 3, j = e & 7;
        int row = (f >> 2) * 32 + (lane >> 4) * 8 + j;
        int col = (f & 3) * 16 + (lane & 15);
        float w = Win[row * 64 + col];
        u16 hi, lo; splt(w, hi, lo);
        WsB[sel * 8192 + rr] = hi;
        WsB[sel * 8192 + 4096 + rr] = lo;
    }
}

// ---------------- dense proj: h = x @ Win (16 nodes/wave, bf16x2 split) -------
__global__ __launch_bounds__(256) void k_proj_mfma(const u16* __restrict__ xh,
                                                   const u16* __restrict__ xl,
                                                   const u16* __restrict__ WinS,
                                                   float* __restrict__ h,
                                                   u16* __restrict__ hbh,
                                                   u16* __restrict__ hbl) {
    int tile = blockIdx.x * 4 + (threadIdx.x >> 6);
    if (tile >= NN / 16) return;
    int lane = threadIdx.x & 63, c = lane & 15, g = lane >> 4;
    int n0 = tile * 16, nr = n0 + c;
    const bf16x8* Wh = (const bf16x8*)WinS;
    const bf16x8* Wl = (const bf16x8*)(WinS + 4096);
    const bf16x8* ph = (const bf16x8*)(xh + (long)nr * 64);
    const bf16x8* pl = (const bf16x8*)(xl + (long)nr * 64);
    bf16x8 A0h = ph[g], A1h = ph[g + 4], A0l = pl[g], A1l = pl[g + 4];
#pragma unroll
    for (int nt = 0; nt < 4; ++nt) {
        f32x4 acc = {0.f, 0.f, 0.f, 0.f};
        acc = MFMA16(A0h, Wh[nt * 64 + lane], acc);
        acc = MFMA16(A1h, Wh[(4 + nt) * 64 + lane], acc);
        acc = MFMA16(A0l, Wh[nt * 64 + lane], acc);
        acc = MFMA16(A1l, Wh[(4 + nt) * 64 + lane], acc);
        acc = MFMA16(A0h, Wl[nt * 64 + lane], acc);
        acc = MFMA16(A1h, Wl[(4 + nt) * 64 + lane], acc);
#pragma unroll
        for (int r = 0; r < 4; ++r) {
            long idx = (long)(n0 + 4 * g + r) * 64 + nt * 16 + c;
            h[idx] = acc[r];
            u16 hi, lo; splt(acc[r], hi, lo);
            hbh[idx] = hi; hbl[idx] = lo;
        }
    }
}

// relu(h) -> bf16 hi/lo mirrors (for the t2 input projection)
__global__ __launch_bounds__(256) void k_relu_split(const float* __restrict__ h,
                                                    u16* __restrict__ rh,
                                                    u16* __restrict__ rl) {
    int gid = blockIdx.x * 256 + threadIdx.x;
    float v = fmaxf(h[gid], 0.f);
    u16 hi, lo; splt(v, hi, lo);
    rh[gid] = hi; rl[gid] = lo;
}

// ---------------- dst-half of GEMM1 + b1, dense 16 nodes/wave ----------------
__global__ __launch_bounds__(256) void k_dsthalf(const u16* __restrict__ hbh,
                                                 const u16* __restrict__ hbl,
                                                 const u16* __restrict__ Wsl,
                                                 const float* __restrict__ b1,
                                                 float* __restrict__ accb) {
    int tile = blockIdx.x * 4 + (threadIdx.x >> 6);
    if (tile >= NN / 16) return;
    int lane = threadIdx.x & 63, c = lane & 15, g = lane >> 4;
    int n0 = tile * 16, nr = n0 + c;
    const bf16x8* W1h = (const bf16x8*)Wsl;
    const bf16x8* W1l = (const bf16x8*)(Wsl + 20480);
    const bf16x8* ph = (const bf16x8*)(hbh + (long)nr * 64);
    const bf16x8* pl = (const bf16x8*)(hbl + (long)nr * 64);
    bf16x8 A0h = ph[g], A1h = ph[g + 4], A0l = pl[g], A1l = pl[g + 4];
#pragma unroll
    for (int nt = 0; nt < 4; ++nt) {
        float bv = b1[nt * 16 + c];
        f32x4 acc = {bv, bv, bv, bv};
        acc = MFMA16(A0h, W1h[(8 + nt) * 64 + lane], acc);
        acc = MFMA16(A1h, W1h[(12 + nt) * 64 + lane], acc);
        acc = MFMA16(A0l, W1h[(8 + nt) * 64 + lane], acc);
        acc = MFMA16(A1l, W1h[(12 + nt) * 64 + lane], acc);
        acc = MFMA16(A0h, W1l[(8 + nt) * 64 + lane], acc);
        acc = MFMA16(A1h, W1l[(12 + nt) * 64 + lane], acc);
#pragma unroll
        for (int r = 0; r < 4; ++r)
            accb[(long)(n0 + 4 * g + r) * 64 + nt * 16 + c] = acc[r];
    }
}

// ---------------- edge MLP + aggregate: one wave per dst node ----------------
__global__ __launch_bounds__(256) void k_edges_mfma(const u16* __restrict__ hbh,
                                                    const u16* __restrict__ hbl,
                                                    u16* __restrict__ aggh,
                                                    u16* __restrict__ aggl,
                                                    const float* __restrict__ d2c,
                                                    const int* __restrict__ rowptr,
                                                    const int* __restrict__ srcc,
                                                    const u16* __restrict__ Wsl,
                                                    const float* __restrict__ W1f,
                                                    const float* __restrict__ accb,
                                                    const float* __restrict__ b2) {
    __shared__ u16 h1h[4][16 * 72];
    __shared__ u16 h1l[4][16 * 72];
    int w = threadIdx.x >> 6, lane = threadIdx.x & 63;
    int node = blockIdx.x * 4 + w;
    int c = lane & 15, g = lane >> 4;
    u16* hlh = h1h[w];
    u16* hll = h1l[w];

    const bf16x8* W1H = (const bf16x8*)Wsl;
    const bf16x8* W2H = (const bf16x8*)(Wsl + 8192);
    const bf16x8* W1L = (const bf16x8*)(Wsl + 20480);
    const bf16x8* W2L = (const bf16x8*)(Wsl + 20480 + 8192);

    bf16x8 w1h[2][4], w1l[2][4], w2h[2][4], w2l[2][4];
#pragma unroll
    for (int ks = 0; ks < 2; ++ks)
#pragma unroll
        for (int nt = 0; nt < 4; ++nt) {
            w1h[ks][nt] = W1H[(ks * 4 + nt) * 64 + lane];
            w1l[ks][nt] = W1L[(ks * 4 + nt) * 64 + lane];
            w2h[ks][nt] = W2H[(ks * 4 + nt) * 64 + lane];
            w2l[ks][nt] = W2L[(ks * 4 + nt) * 64 + lane];
        }
    float base_c[4], wdc[4];
#pragma unroll
    for (int nt = 0; nt < 4; ++nt) {
        base_c[nt] = accb[(long)node * 64 + nt * 16 + c];
        wdc[nt] = W1f[128 * 64 + nt * 16 + c];
    }
    float b2c = b2[lane];

    int e0 = rowptr[node], e1 = rowptr[node + 1];
    f32x4 z = {0.f, 0.f, 0.f, 0.f};
    f32x4 acc2[4] = {z, z, z, z};

    for (int te = e0; te < e1; te += 16) {
        int t = te + c;
        if (t > e1 - 1) t = e1 - 1;
        int s = srcc[t];
        const bf16x8* sph = (const bf16x8*)(hbh + (long)s * 64);
        const bf16x8* spl = (const bf16x8*)(hbl + (long)s * 64);
        bf16x8 A0h = sph[g], A1h = sph[g + 4];
        bf16x8 A0l = spl[g], A1l = spl[g + 4];
        float dq[4];
#pragma unroll
        for (int r = 0; r < 4; ++r) dq[r] = d2c[te + 4 * g + r];
        int rem = e1 - te;
        f32x4 a1[4];
#pragma unroll
        for (int nt = 0; nt < 4; ++nt) {
            f32x4 ci;
#pragma unroll
            for (int r = 0; r < 4; ++r) ci[r] = base_c[nt] + dq[r] * wdc[nt];
            ci = MFMA16(A0h, w1h[0][nt], ci);
            ci = MFMA16(A1h, w1h[1][nt], ci);
            ci = MFMA16(A0l, w1h[0][nt], ci);
            ci = MFMA16(A1l, w1h[1][nt], ci);
            ci = MFMA16(A0h, w1l[0][nt], ci);
            ci = MFMA16(A1h, w1l[1][nt], ci);
            a1[nt] = ci;
        }
#pragma unroll
        for (int nt = 0; nt < 4; ++nt)
#pragma unroll
            for (int r = 0; r < 4; ++r) {
                int m = 4 * g + r;
                float v = (m < rem) ? fmaxf(a1[nt][r], 0.f) : 0.f;
                u16 hi, lo; splt(v, hi, lo);
                hlh[m * 72 + nt * 16 + c] = hi;
                hll[m * 72 + nt * 16 + c] = lo;
            }
        bf16x8 F0h = *(const bf16x8*)(hlh + c * 72 + g * 8);
        bf16x8 F1h = *(const bf16x8*)(hlh + c * 72 + 32 + g * 8);
        bf16x8 F0l = *(const bf16x8*)(hll + c * 72 + g * 8);
        bf16x8 F1l = *(const bf16x8*)(hll + c * 72 + 32 + g * 8);
#pragma unroll
        for (int nt = 0; nt < 4; ++nt) {
            acc2[nt] = MFMA16(F0h, w2h[0][nt], acc2[nt]);
            acc2[nt] = MFMA16(F1h, w2h[1][nt], acc2[nt]);
            acc2[nt] = MFMA16(F0l, w2h[0][nt], acc2[nt]);
            acc2[nt] = MFMA16(F1l, w2h[1][nt], acc2[nt]);
            acc2[nt] = MFMA16(F0h, w2l[0][nt], acc2[nt]);
            acc2[nt] = MFMA16(F1h, w2l[1][nt], acc2[nt]);
        }
    }

    float deg = (float)(e1 - e0);
    float sv[4];
#pragma unroll
    for (int nt = 0; nt < 4; ++nt) {
        float s = acc2[nt][0] + acc2[nt][1] + acc2[nt][2] + acc2[nt][3];
        s += __shfl_xor(s, 16);
        s += __shfl_xor(s, 32);
        sv[nt] = s;
    }
    float v = sv[0];
    v = (g == 1) ? sv[1] : v;
    v = (g == 2) ? sv[2] : v;
    v = (g == 3) ? sv[3] : v;
    v += deg * b2c;
    u16 hi, lo; splt(v, hi, lo);
    aggh[(long)node * 64 + lane] = hi;
    aggl[(long)node * 64 + lane] = lo;
}

// ---------------- node update: h += relu([h,agg]@W3 + b3), 16 nodes/wave -----
__global__ __launch_bounds__(256) void k_node_mfma(float* __restrict__ h,
                                                   u16* __restrict__ hbh,
                                                   u16* __restrict__ hbl,
                                                   const u16* __restrict__ aggh,
                                                   const u16* __restrict__ aggl,
                                                   const u16* __restrict__ Wsl,
                                                   const float* __restrict__ b3) {
    int tile = blockIdx.x * 4 + (threadIdx.x >> 6);
    if (tile >= NN / 16) return;
    int lane = threadIdx.x & 63, c = lane & 15, g = lane >> 4;
    int n0 = tile * 16, nr = n0 + c;
    const bf16x8* W3H = (const bf16x8*)(Wsl + 12288);
    const bf16x8* W3L = (const bf16x8*)(Wsl + 20480 + 12288);
    const bf16x8* phh = (const bf16x8*)(hbh + (long)nr * 64);
    const bf16x8* phl = (const bf16x8*)(hbl + (long)nr * 64);
    const bf16x8* pah = (const bf16x8*)(aggh + (long)nr * 64);
    const bf16x8* pal = (const bf16x8*)(aggl + (long)nr * 64);
    bf16x8 Ah0h = phh[g], Ah1h = phh[g + 4], Ah0l = phl[g], Ah1l = phl[g + 4];
    bf16x8 Aa0h = pah[g], Aa1h = pah[g + 4], Aa0l = pal[g], Aa1l = pal[g + 4];
#pragma unroll
    for (int nt = 0; nt < 4; ++nt) {
        float bv = b3[nt * 16 + c];
        f32x4 acc = {bv, bv, bv, bv};
        acc = MFMA16(Ah0h, W3H[nt * 64 + lane], acc);
        acc = MFMA16(Ah1h, W3H[(4 + nt) * 64 + lane], acc);
        acc = MFMA16(Aa0h, W3H[(8 + nt) * 64 + lane], acc);
        acc = MFMA16(Aa1h, W3H[(12 + nt) * 64 + lane], acc);
        acc = MFMA16(Ah0l, W3H[nt * 64 + lane], acc);
        acc = MFMA16(Ah1l, W3H[(4 + nt) * 64 + lane], acc);
        acc = MFMA16(Aa0l, W3H[(8 + nt) * 64 + lane], acc);
        acc = MFMA16(Aa1l, W3H[(12 + nt) * 64 + lane], acc);
        acc = MFMA16(Ah0h, W3L[nt * 64 + lane], acc);
        acc = MFMA16(Ah1h, W3L[(4 + nt) * 64 + lane], acc);
        acc = MFMA16(Aa0h, W3L[(8 + nt) * 64 + lane], acc);
        acc = MFMA16(Aa1h, W3L[(12 + nt) * 64 + lane], acc);
#pragma unroll
        for (int r = 0; r < 4; ++r) {
            long idx = (long)(n0 + 4 * g + r) * 64 + nt * 16 + c;
            float ho = h[idx];
            float hn = ho + fmaxf(acc[r], 0.f);
            h[idx] = hn;
            u16 hi, lo; splt(hn, hi, lo);
            hbh[idx] = hi; hbl[idx] = lo;
        }
    }
}

// ---------------- pooling: atomic-free via sorted-batch ranges ----------------
// gpt[g] = lower_bound(batch, g); gpt[64] = N
__global__ void k_granges(const int* __restrict__ batch, int* __restrict__ gpt) {
    int g = blockIdx.x * blockDim.x + threadIdx.x;
    if (g > 64) return;
    int lo = 0, hi = NN;
    while (lo < hi) {
        int mid = (lo + hi) >> 1;
        if (batch[mid] < g) lo = mid + 1; else hi = mid;
    }
    gpt[g] = lo;
}

// sumh[g,64] = sum over graph-g nodes of relu(h); 8 splits/graph, 64 atomics/block
__global__ __launch_bounds__(256) void k_sumrelu(const float* __restrict__ h,
                                                 const int* __restrict__ gpt,
                                                 float* __restrict__ sumh) {
    int g = blockIdx.x >> 3, sp = blockIdx.x & 7;
    int lo = gpt[g], hi = gpt[g + 1];
    int n = hi - lo;
    int per = (n + 7) / 8;
    int s0 = lo + sp * per;
    int s1 = s0 + per; if (s1 > hi) s1 = hi;
    int lane = threadIdx.x & 63, wv = threadIdx.x >> 6;
    float acc = 0.f;
    for (int i = s0 + wv; i < s1; i += 4)
        acc += fmaxf(h[(long)i * 64 + lane], 0.f);
    if (acc != 0.f || wv == 0)
        atomicAdd(&sumh[g * 64 + lane], acc);
}

// out[g,o] = (sumh[g,:] @ Wlin[:,o]) / cnt + blin[o]   (cnt==0 -> 0, matches clip)
__global__ __launch_bounds__(256) void k_outgemm(const float* __restrict__ sumh,
                                                 const int* __restrict__ gpt,
                                                 const float* __restrict__ Wlin,
                                                 const float* __restrict__ blin,
                                                 float* __restrict__ out) {
    int idx = blockIdx.x * 256 + threadIdx.x;
    if (idx >= 64 * 32) return;
    int g = idx >> 5, o = idx & 31;
    int cnt = gpt[g + 1] - gpt[g];
    float acc = 0.f;
#pragma unroll 8
    for (int k = 0; k < 64; ++k)
        acc += sumh[g * 64 + k] * Wlin[k * 32 + o];
    out[idx] = (cnt > 0) ? (acc / (float)cnt + blin[o]) : 0.f;
}

extern "C" void kernel_launch(void* const* d_in, const int* in_sizes, int n_in,
                              void* d_out, int out_size, void* d_ws, size_t ws_size,
                              hipStream_t stream) {
    const float* pos    = (const float*)d_in[0];
    const int*   z      = (const int*)d_in[1];
    const int*   ei     = (const int*)d_in[2];
    const int*   batch  = (const int*)d_in[3];
    const float* emb    = (const float*)d_in[4];
    const float* t1_Win = (const float*)d_in[5];
    const float* t1_W1  = (const float*)d_in[6];
    const float* t1_b1  = (const float*)d_in[7];
    const float* t1_W2  = (const float*)d_in[8];
    const float* t1_b2  = (const float*)d_in[9];
    const float* t1_W3  = (const float*)d_in[10];
    const float* t1_b3  = (const float*)d_in[11];
    const float* t2_Win = (const float*)d_in[12];
    const float* t2_W1  = (const float*)d_in[13];
    const float* t2_b1  = (const float*)d_in[14];
    const float* t2_W2  = (const float*)d_in[15];
    const float* t2_b2  = (const float*)d_in[16];
    const float* t2_W3  = (const float*)d_in[17];
    const float* t2_b3  = (const float*)d_in[18];
    const float* Wlin   = (const float*)d_in[19];
    const float* blin   = (const float*)d_in[20];

    const int* srcI = ei;
    const int* dstI = ei + EE;

    char* ws = (char*)d_ws;
    size_t off = 0;
    auto alloc = [&](size_t bytes) -> void* {
        void* p = ws + off;
        off += (bytes + 255) / 256 * 256;
        return p;
    };
    float* bufH   = (float*)alloc((size_t)NN * 64 * 4);   // h master (fp32)
    float* accb   = (float*)alloc((size_t)NN * 64 * 4);   // dst-half+b1; aliases x mirrors
    u16*   hbh    = (u16*)alloc((size_t)NN * 64 * 2);
    u16*   hbl    = (u16*)alloc((size_t)NN * 64 * 2);
    u16*   aggh   = (u16*)alloc((size_t)NN * 64 * 2);
    u16*   aggl   = (u16*)alloc((size_t)NN * 64 * 2);
    int*   rowptr = (int*)alloc((size_t)(NN + 1) * 4);
    int*   cursor = (int*)alloc((size_t)NN * 4);
    int*   srcc   = (int*)alloc((size_t)EE * 4);
    float* d2c    = (float*)alloc((size_t)(EE + 16) * 4);
    int*   gpt    = (int*)alloc(65 * 4);
    float* sumh   = (float*)alloc(64 * 64 * 4);
    u16*   WsA    = (u16*)alloc((size_t)8 * 40960 * 2);
    u16*   WsB    = (u16*)alloc((size_t)16384 * 2);

    u16* xh = (u16*)accb;
    u16* xl = (u16*)accb + (size_t)NN * 64;

    const int NTB = (NN / 16 + 3) / 4 + 1;   // 1563 blocks of 4 node-tiles
    const int NB  = NN / 4;                  // 25000 blocks (wave per node)

    // prologue: embed + CSR + weight swizzle + graph ranges
    k_embed<<<NN * 64 / 256, 256, 0, stream>>>(pos, z, emb, xh, xl);
    hipMemsetAsync(cursor, 0, (size_t)NN * 4, stream);
    k_deg<<<(EE + 255) / 256, 256, 0, stream>>>(dstI, cursor);
    k_scan<<<1, 1024, 0, stream>>>(cursor, rowptr);
    hipMemcpyAsync(cursor, rowptr, (size_t)NN * 4, hipMemcpyDeviceToDevice, stream);
    k_scatter<<<(EE + 255) / 256, 256, 0, stream>>>(srcI, dstI, pos, cursor, srcc, d2c);
    k_swz<<<172032 / 256, 256, 0, stream>>>(t1_W1, t1_W2, t1_W3, t2_W1, t2_W2, t2_W3,
                                            t1_Win, t2_Win, WsA, WsB);
    k_granges<<<1, 128, 0, stream>>>(batch, gpt);

    // transformer 1
    k_proj_mfma<<<NTB, 256, 0, stream>>>(xh, xl, WsB, bufH, hbh, hbl);
    for (int l = 0; l < 4; ++l) {
        const u16* Wsl = WsA + (size_t)l * 40960;
        k_dsthalf<<<NTB, 256, 0, stream>>>(hbh, hbl, Wsl, t1_b1 + (size_t)l * 64, accb);
        k_edges_mfma<<<NB, 256, 0, stream>>>(hbh, hbl, aggh, aggl, d2c, rowptr, srcc,
                                             Wsl, t1_W1 + (size_t)l * 129 * 64, accb,
                                             t1_b2 + (size_t)l * 64);
        k_node_mfma<<<NTB, 256, 0, stream>>>(bufH, hbh, hbl, aggh, aggl, Wsl,
                                             t1_b3 + (size_t)l * 64);
    }

    // transformer 2
    k_relu_split<<<NN * 64 / 256, 256, 0, stream>>>(bufH, xh, xl);
    k_proj_mfma<<<NTB, 256, 0, stream>>>(xh, xl, WsB + 8192, bufH, hbh, hbl);
    for (int l = 0; l < 4; ++l) {
        const u16* Wsl = WsA + (size_t)(4 + l) * 40960;
        k_dsthalf<<<NTB, 256, 0, stream>>>(hbh, hbl, Wsl, t2_b1 + (size_t)l * 64, accb);
        k_edges_mfma<<<NB, 256, 0, stream>>>(hbh, hbl, aggh, aggl, d2c, rowptr, srcc,
                                             Wsl, t2_W1 + (size_t)l * 129 * 64, accb,
                                             t2_b2 + (size_t)l * 64);
        k_node_mfma<<<NTB, 256, 0, stream>>>(bufH, hbh, hbl, aggh, aggl, Wsl,
                                             t2_b3 + (size_t)l * 64);
    }

    // pooled mean — atomic-light path
    hipMemsetAsync(sumh, 0, 64 * 64 * 4, stream);
    k_sumrelu<<<64 * 8, 256, 0, stream>>>(bufH, gpt, sumh);
    k_outgemm<<<8, 256, 0, stream>>>(sumh, gpt, Wlin, blin, (float*)d_out);
}

// Round 6
// 1552.177 us; speedup vs baseline: 6.1013x; 1.5137x over previous
//
#include <hip/hip_runtime.h>
#include <hip/hip_bf16.h>

typedef unsigned short u16;
typedef unsigned int   u32;
typedef short bf16x8 __attribute__((ext_vector_type(8)));
typedef float f32x4  __attribute__((ext_vector_type(4)));

#define NN 100000
#define EE 800000
#define NTILE 6250            // NN/16
#define NTB   1563            // ceil(NTILE/4)
#define EBLK  2048            // persistent edge blocks
#define TOTW  (EBLK * 4)      // persistent edge waves

#define MFMA16(a,b,c) __builtin_amdgcn_mfma_f32_16x16x32_bf16(a,b,c,0,0,0)

__device__ __forceinline__ float b2f(u16 u) {
    u32 x = ((u32)u) << 16;
    return __uint_as_float(x);
}
__device__ __forceinline__ u16 f2b(float f) {
    __hip_bfloat16 h = __float2bfloat16(f);
    return *reinterpret_cast<u16*>(&h);
}
__device__ __forceinline__ void splt(float v, u16& hi, u16& lo) {
    hi = f2b(v);
    lo = f2b(v - b2f(hi));
}

// ---------------- embed: xc[i][0..63]=hi, [64..127]=lo of [pos|emb[z]] -------
__global__ __launch_bounds__(256) void k_embed(const float* __restrict__ pos,
                                               const int* __restrict__ z,
                                               const float* __restrict__ emb,
                                               u16* __restrict__ xc) {
    int gid = blockIdx.x * 256 + threadIdx.x;   // N*64 exactly
    int i = gid >> 6, f = gid & 63;
    float v = (f < 3) ? pos[i * 3 + f] : emb[(long)z[i] * 61 + (f - 3)];
    u16 hi, lo; splt(v, hi, lo);
    xc[(long)i * 128 + f] = hi;
    xc[(long)i * 128 + 64 + f] = lo;
}

// relu(h) -> combined hi/lo mirror
__global__ __launch_bounds__(256) void k_relu_split(const float* __restrict__ h,
                                                    u16* __restrict__ xc) {
    int gid = blockIdx.x * 256 + threadIdx.x;
    int i = gid >> 6, f = gid & 63;
    float v = fmaxf(h[gid], 0.f);
    u16 hi, lo; splt(v, hi, lo);
    xc[(long)i * 128 + f] = hi;
    xc[(long)i * 128 + 64 + f] = lo;
}

// ---------------- CSR build ----------------
__global__ __launch_bounds__(256) void k_deg(const int* __restrict__ dst,
                                             int* __restrict__ deg) {
    int e = blockIdx.x * 256 + threadIdx.x;
    if (e < EE) atomicAdd(&deg[dst[e]], 1);
}

// fast single-block chunked scan: each thread owns 98 contiguous elements
__global__ __launch_bounds__(1024) void k_scan(const int* __restrict__ deg,
                                               int* __restrict__ rowptr) {
    __shared__ int s[1024];
    const int CH = 98;                      // 1024*98 >= NN
    int tid = threadIdx.x;
    int t0 = tid * CH;
    int sum = 0;
#pragma unroll 2
    for (int i = 0; i < CH; ++i) {
        int ix = t0 + i;
        if (ix < NN) sum += deg[ix];
    }
    s[tid] = sum;
    __syncthreads();
    for (int off = 1; off < 1024; off <<= 1) {
        int t = (tid >= off) ? s[tid - off] : 0;
        __syncthreads();
        s[tid] += t;
        __syncthreads();
    }
    int pre = s[tid] - sum;                 // exclusive prefix
    int run = pre;
    for (int i = 0; i < CH; ++i) {
        int ix = t0 + i;
        if (ix < NN) { rowptr[ix] = run; run += deg[ix]; }
    }
    if (tid == 1023) rowptr[NN] = pre;      // t0 >= NN here, pre == total == EE
}

// scatter edges into CSR slots; computes d2 inline (segment order irrelevant)
__global__ __launch_bounds__(256) void k_scatter(const int* __restrict__ src,
                                                 const int* __restrict__ dst,
                                                 const float* __restrict__ pos,
                                                 int* __restrict__ cursor,
                                                 int* __restrict__ srcc,
                                                 float* __restrict__ d2c) {
    int e = blockIdx.x * 256 + threadIdx.x;
    if (e >= EE) return;
    int d = dst[e], s = src[e];
    int p = atomicAdd(&cursor[d], 1);
    srcc[p] = s;
    float dx = pos[s * 3 + 0] - pos[d * 3 + 0];
    float dy = pos[s * 3 + 1] - pos[d * 3 + 1];
    float dz = pos[s * 3 + 2] - pos[d * 3 + 2];
    d2c[p] = dx * dx + dy * dy + dz * dz;
}

// ---------------- weight swizzle (fp32 -> bf16 hi/lo B-frags) ----------------
// Layer block L (0..7) in WsA (u16): [W1hi 8192][W2hi 4096][W3hi 8192] then lo @+20480
// WsB: [Win1 hi 4096][Win1 lo 4096][Win2 hi 4096][Win2 lo 4096]
__global__ __launch_bounds__(256) void k_swz(const float* t1W1, const float* t1W2, const float* t1W3,
                                             const float* t2W1, const float* t2W2, const float* t2W3,
                                             const float* t1Win, const float* t2Win,
                                             u16* __restrict__ WsA, u16* __restrict__ WsB) {
    int gid = blockIdx.x * 256 + threadIdx.x;   // 172032 exactly
    if (gid < 163840) {
        int L = gid / 20480;
        int r = gid % 20480;
        const float* W1 = (L < 4 ? t1W1 : t2W1) + (size_t)(L & 3) * 129 * 64;
        const float* W2 = (L < 4 ? t1W2 : t2W2) + (size_t)(L & 3) * 64 * 64;
        const float* W3 = (L < 4 ? t1W3 : t2W3) + (size_t)(L & 3) * 128 * 64;
        float w;
        int rr, f, e, lane, j, row, col;
        if (r < 8192) { rr = r; f = rr >> 9; e = rr & 511; lane = e >> 3; j = e & 7;
            row = (f >> 2) * 32 + (lane >> 4) * 8 + j; col = (f & 3) * 16 + (lane & 15);
            w = W1[row * 64 + col];
        } else if (r < 12288) { rr = r - 8192; f = rr >> 9; e = rr & 511; lane = e >> 3; j = e & 7;
            row = (f >> 2) * 32 + (lane >> 4) * 8 + j; col = (f & 3) * 16 + (lane & 15);
            w = W2[row * 64 + col];
        } else { rr = r - 12288; f = rr >> 9; e = rr & 511; lane = e >> 3; j = e & 7;
            row = (f >> 2) * 32 + (lane >> 4) * 8 + j; col = (f & 3) * 16 + (lane & 15);
            w = W3[row * 64 + col];
        }
        u16 hi, lo; splt(w, hi, lo);
        WsA[(size_t)L * 40960 + r] = hi;
        WsA[(size_t)L * 40960 + 20480 + r] = lo;
    } else {
        int t = gid - 163840;
        int sel = (t < 4096) ? 0 : 1;
        int rr = t & 4095;
        const float* Win = sel ? t2Win : t1Win;
        int f = rr >> 9, e = rr & 511, lane = e >> 3, j = e & 7;
        int row = (f >> 2) * 32 + (lane >> 4) * 8 + j;
        int col = (f & 3) * 16 + (lane & 15);
        float w = Win[row * 64 + col];
        u16 hi, lo; splt(w, hi, lo);
        WsB[sel * 8192 + rr] = hi;
        WsB[sel * 8192 + 4096 + rr] = lo;
    }
}

// ---------------- dense proj: h = x @ Win (16 nodes/wave, bf16x2 split) -------
__global__ __launch_bounds__(256) void k_proj_mfma(const u16* __restrict__ xc,
                                                   const u16* __restrict__ WinS,
                                                   float* __restrict__ h,
                                                   u16* __restrict__ hbx) {
    int tile = blockIdx.x * 4 + (threadIdx.x >> 6);
    if (tile >= NTILE) return;
    int lane = threadIdx.x & 63, c = lane & 15, g = lane >> 4;
    int n0 = tile * 16, nr = n0 + c;
    const bf16x8* Wh = (const bf16x8*)WinS;
    const bf16x8* Wl = (const bf16x8*)(WinS + 4096);
    const bf16x8* p = (const bf16x8*)(xc + (long)nr * 128);
    bf16x8 A0h = p[g], A1h = p[g + 4], A0l = p[g + 8], A1l = p[g + 12];
#pragma unroll
    for (int nt = 0; nt < 4; ++nt) {
        f32x4 acc = {0.f, 0.f, 0.f, 0.f};
        acc = MFMA16(A0h, Wh[nt * 64 + lane], acc);
        acc = MFMA16(A1h, Wh[(4 + nt) * 64 + lane], acc);
        acc = MFMA16(A0l, Wh[nt * 64 + lane], acc);
        acc = MFMA16(A1l, Wh[(4 + nt) * 64 + lane], acc);
        acc = MFMA16(A0h, Wl[nt * 64 + lane], acc);
        acc = MFMA16(A1h, Wl[(4 + nt) * 64 + lane], acc);
#pragma unroll
        for (int r = 0; r < 4; ++r) {
            long n = n0 + 4 * g + r;
            h[n * 64 + nt * 16 + c] = acc[r];
            u16 hi, lo; splt(acc[r], hi, lo);
            hbx[n * 128 + nt * 16 + c] = hi;
            hbx[n * 128 + 64 + nt * 16 + c] = lo;
        }
    }
}

// ---------------- standalone dst-half of GEMM1 + b1 (layer 0 only) -----------
__global__ __launch_bounds__(256) void k_dsthalf(const u16* __restrict__ hbx,
                                                 const u16* __restrict__ Wsl,
                                                 const float* __restrict__ b1,
                                                 float* __restrict__ accb) {
    int tile = blockIdx.x * 4 + (threadIdx.x >> 6);
    if (tile >= NTILE) return;
    int lane = threadIdx.x & 63, c = lane & 15, g = lane >> 4;
    int n0 = tile * 16, nr = n0 + c;
    const bf16x8* W1h = (const bf16x8*)Wsl;
    const bf16x8* W1l = (const bf16x8*)(Wsl + 20480);
    const bf16x8* p = (const bf16x8*)(hbx + (long)nr * 128);
    bf16x8 A0h = p[g], A1h = p[g + 4], A0l = p[g + 8], A1l = p[g + 12];
#pragma unroll
    for (int nt = 0; nt < 4; ++nt) {
        float bv = b1[nt * 16 + c];
        f32x4 acc = {bv, bv, bv, bv};
        acc = MFMA16(A0h, W1h[(8 + nt) * 64 + lane], acc);
        acc = MFMA16(A1h, W1h[(12 + nt) * 64 + lane], acc);
        acc = MFMA16(A0l, W1h[(8 + nt) * 64 + lane], acc);
        acc = MFMA16(A1l, W1h[(12 + nt) * 64 + lane], acc);
        acc = MFMA16(A0h, W1l[(8 + nt) * 64 + lane], acc);
        acc = MFMA16(A1h, W1l[(12 + nt) * 64 + lane], acc);
#pragma unroll
        for (int r = 0; r < 4; ++r)
            accb[(long)(n0 + 4 * g + r) * 64 + nt * 16 + c] = acc[r];
    }
}

// ---------------- edge kernel: GEMM1 + relu + row-sum -> S[node] -------------
// persistent: wave w handles nodes w, w+TOTW, ... ; no LDS, no per-edge GEMM2
__global__ __launch_bounds__(256) void k_edges_mfma(const u16* __restrict__ hbx,
                                                    u16* __restrict__ agx,
                                                    const float* __restrict__ d2c,
                                                    const int* __restrict__ rowptr,
                                                    const int* __restrict__ srcc,
                                                    const u16* __restrict__ Wsl,
                                                    const float* __restrict__ W1f,
                                                    const float* __restrict__ accb) {
    int lane = threadIdx.x & 63;
    int wid = blockIdx.x * 4 + (threadIdx.x >> 6);
    int c = lane & 15, g = lane >> 4;
    const bf16x8* W1H = (const bf16x8*)Wsl;
    const bf16x8* W1L = (const bf16x8*)(Wsl + 20480);
    // stationary: src-half of W1, hi+lo (16 frags, register-resident)
    bf16x8 w1h[2][4], w1l[2][4];
#pragma unroll
    for (int ks = 0; ks < 2; ++ks)
#pragma unroll
        for (int nt = 0; nt < 4; ++nt) {
            w1h[ks][nt] = W1H[(ks * 4 + nt) * 64 + lane];
            w1l[ks][nt] = W1L[(ks * 4 + nt) * 64 + lane];
        }
    float wdc[4];
#pragma unroll
    for (int nt = 0; nt < 4; ++nt) wdc[nt] = W1f[128 * 64 + nt * 16 + c];

    for (int node = wid; node < NN; node += TOTW) {
        float base_c[4];
#pragma unroll
        for (int nt = 0; nt < 4; ++nt)
            base_c[nt] = accb[(long)node * 64 + nt * 16 + c];
        int e0 = rowptr[node], e1 = rowptr[node + 1];
        f32x4 z = {0.f, 0.f, 0.f, 0.f};
        f32x4 acc[4] = {z, z, z, z};

        for (int te = e0; te < e1; te += 16) {
            int t = te + c;
            if (t > e1 - 1) t = e1 - 1;
            int s = srcc[t];
            const bf16x8* sp = (const bf16x8*)(hbx + (long)s * 128);
            bf16x8 A0h = sp[g], A1h = sp[g + 4], A0l = sp[g + 8], A1l = sp[g + 12];
            float dq[4];
#pragma unroll
            for (int r = 0; r < 4; ++r) dq[r] = d2c[te + 4 * g + r];
            int rem = e1 - te;
#pragma unroll
            for (int nt = 0; nt < 4; ++nt) {
                f32x4 ci;
#pragma unroll
                for (int r = 0; r < 4; ++r) ci[r] = base_c[nt] + dq[r] * wdc[nt];
                ci = MFMA16(A0h, w1h[0][nt], ci);
                ci = MFMA16(A1h, w1h[1][nt], ci);
                ci = MFMA16(A0l, w1h[0][nt], ci);
                ci = MFMA16(A1l, w1h[1][nt], ci);
                ci = MFMA16(A0h, w1l[0][nt], ci);
                ci = MFMA16(A1h, w1l[1][nt], ci);
#pragma unroll
                for (int r = 0; r < 4; ++r)
                    acc[nt][r] += (4 * g + r < rem) ? fmaxf(ci[r], 0.f) : 0.f;
            }
        }
        // reduce rows (edges) -> per-col sums; lane owns col==lane
        float sv[4];
#pragma unroll
        for (int nt = 0; nt < 4; ++nt) {
            float s = acc[nt][0] + acc[nt][1] + acc[nt][2] + acc[nt][3];
            s += __shfl_xor(s, 16);
            s += __shfl_xor(s, 32);
            sv[nt] = s;
        }
        float v = sv[0];
        v = (g == 1) ? sv[1] : v;
        v = (g == 2) ? sv[2] : v;
        v = (g == 3) ? sv[3] : v;
        u16 hi, lo; splt(v, hi, lo);
        agx[(long)node * 128 + lane] = hi;
        agx[(long)node * 128 + 64 + lane] = lo;
    }
}

// ---------------- fused dense kernel: agg = S@W2 + deg*b2 ; h += relu([h,agg]@W3+b3)
// ; optionally accb_next = h_new @ W1next(dst-half) + b1next
__global__ __launch_bounds__(256) void k_node2(float* __restrict__ h,
                                               u16* __restrict__ hbx,
                                               const u16* __restrict__ agx,
                                               const u16* __restrict__ Wsl,
                                               const float* __restrict__ b2,
                                               const float* __restrict__ b3,
                                               const int* __restrict__ rowptr,
                                               const u16* __restrict__ WslN,
                                               const float* __restrict__ b1N,
                                               float* __restrict__ accb) {
    __shared__ u16 th[4][16 * 72];
    __shared__ u16 tl[4][16 * 72];
    int w = threadIdx.x >> 6, lane = threadIdx.x & 63;
    int tile = blockIdx.x * 4 + w;
    if (tile >= NTILE) return;
    int c = lane & 15, g = lane >> 4;
    int n0 = tile * 16, nr = n0 + c;
    u16* lh = th[w];
    u16* ll = tl[w];

    const bf16x8* W2H = (const bf16x8*)(Wsl + 8192);
    const bf16x8* W2L = (const bf16x8*)(Wsl + 28672);
    const bf16x8* W3H = (const bf16x8*)(Wsl + 12288);
    const bf16x8* W3L = (const bf16x8*)(Wsl + 32768);

    const bf16x8* sp = (const bf16x8*)(agx + (long)nr * 128);
    bf16x8 S0h = sp[g], S1h = sp[g + 4], S0l = sp[g + 8], S1l = sp[g + 12];
    const bf16x8* hp = (const bf16x8*)(hbx + (long)nr * 128);
    bf16x8 H0h = hp[g], H1h = hp[g + 4], H0l = hp[g + 8], H1l = hp[g + 12];

    float dg[4];
#pragma unroll
    for (int r = 0; r < 4; ++r) {
        int n = n0 + 4 * g + r;
        dg[r] = (float)(rowptr[n + 1] - rowptr[n]);
    }

    // GEMM2: agg (C-layout) -> LDS transpose planes
#pragma unroll
    for (int nt = 0; nt < 4; ++nt) {
        float b2c = b2[nt * 16 + c];
        f32x4 a = {dg[0] * b2c, dg[1] * b2c, dg[2] * b2c, dg[3] * b2c};
        a = MFMA16(S0h, W2H[nt * 64 + lane], a);
        a = MFMA16(S1h, W2H[(4 + nt) * 64 + lane], a);
        a = MFMA16(S0l, W2H[nt * 64 + lane], a);
        a = MFMA16(S1l, W2H[(4 + nt) * 64 + lane], a);
        a = MFMA16(S0h, W2L[nt * 64 + lane], a);
        a = MFMA16(S1h, W2L[(4 + nt) * 64 + lane], a);
#pragma unroll
        for (int r = 0; r < 4; ++r) {
            u16 hi, lo; splt(a[r], hi, lo);
            lh[(4 * g + r) * 72 + nt * 16 + c] = hi;
            ll[(4 * g + r) * 72 + nt * 16 + c] = lo;
        }
    }
    bf16x8 G0h = *(const bf16x8*)(lh + c * 72 + g * 8);
    bf16x8 G1h = *(const bf16x8*)(lh + c * 72 + 32 + g * 8);
    bf16x8 G0l = *(const bf16x8*)(ll + c * 72 + g * 8);
    bf16x8 G1l = *(const bf16x8*)(ll + c * 72 + 32 + g * 8);

    // GEMM3: u = [h, agg] @ W3 + b3
    f32x4 u4[4];
#pragma unroll
    for (int nt = 0; nt < 4; ++nt) {
        float bv = b3[nt * 16 + c];
        f32x4 u = {bv, bv, bv, bv};
        u = MFMA16(H0h, W3H[nt * 64 + lane], u);
        u = MFMA16(H1h, W3H[(4 + nt) * 64 + lane], u);
        u = MFMA16(G0h, W3H[(8 + nt) * 64 + lane], u);
        u = MFMA16(G1h, W3H[(12 + nt) * 64 + lane], u);
        u = MFMA16(H0l, W3H[nt * 64 + lane], u);
        u = MFMA16(H1l, W3H[(4 + nt) * 64 + lane], u);
        u = MFMA16(G0l, W3H[(8 + nt) * 64 + lane], u);
        u = MFMA16(G1l, W3H[(12 + nt) * 64 + lane], u);
        u = MFMA16(H0h, W3L[nt * 64 + lane], u);
        u = MFMA16(H1h, W3L[(4 + nt) * 64 + lane], u);
        u = MFMA16(G0h, W3L[(8 + nt) * 64 + lane], u);
        u = MFMA16(G1h, W3L[(12 + nt) * 64 + lane], u);
        u4[nt] = u;
    }

    // h update + hbx write + stash h_new for next-layer dst-half
#pragma unroll
    for (int nt = 0; nt < 4; ++nt)
#pragma unroll
        for (int r = 0; r < 4; ++r) {
            long n = n0 + 4 * g + r;
            long idx = n * 64 + nt * 16 + c;
            float hn = h[idx] + fmaxf(u4[nt][r], 0.f);
            h[idx] = hn;
            u16 hi, lo; splt(hn, hi, lo);
            hbx[n * 128 + nt * 16 + c] = hi;
            hbx[n * 128 + 64 + nt * 16 + c] = lo;
            lh[(4 * g + r) * 72 + nt * 16 + c] = hi;
            ll[(4 * g + r) * 72 + nt * 16 + c] = lo;
        }

    if (WslN) {
        bf16x8 N0h = *(const bf16x8*)(lh + c * 72 + g * 8);
        bf16x8 N1h = *(const bf16x8*)(lh + c * 72 + 32 + g * 8);
        bf16x8 N0l = *(const bf16x8*)(ll + c * 72 + g * 8);
        bf16x8 N1l = *(const bf16x8*)(ll + c * 72 + 32 + g * 8);
        const bf16x8* W1h = (const bf16x8*)WslN;
        const bf16x8* W1l = (const bf16x8*)(WslN + 20480);
#pragma unroll
        for (int nt = 0; nt < 4; ++nt) {
            float bv = b1N[nt * 16 + c];
            f32x4 a = {bv, bv, bv, bv};
            a = MFMA16(N0h, W1h[(8 + nt) * 64 + lane], a);
            a = MFMA16(N1h, W1h[(12 + nt) * 64 + lane], a);
            a = MFMA16(N0l, W1h[(8 + nt) * 64 + lane], a);
            a = MFMA16(N1l, W1h[(12 + nt) * 64 + lane], a);
            a = MFMA16(N0h, W1l[(8 + nt) * 64 + lane], a);
            a = MFMA16(N1h, W1l[(12 + nt) * 64 + lane], a);
#pragma unroll
            for (int r = 0; r < 4; ++r)
                accb[(long)(n0 + 4 * g + r) * 64 + nt * 16 + c] = a[r];
        }
    }
}

// ---------------- pooling: atomic-light via sorted-batch ranges ---------------
__global__ void k_granges(const int* __restrict__ batch, int* __restrict__ gpt) {
    int g = blockIdx.x * blockDim.x + threadIdx.x;
    if (g > 64) return;
    int lo = 0, hi = NN;
    while (lo < hi) {
        int mid = (lo + hi) >> 1;
        if (batch[mid] < g) lo = mid + 1; else hi = mid;
    }
    gpt[g] = lo;
}

__global__ __launch_bounds__(256) void k_sumrelu(const float* __restrict__ h,
                                                 const int* __restrict__ gpt,
                                                 float* __restrict__ sumh) {
    int g = blockIdx.x >> 3, sp = blockIdx.x & 7;
    int lo = gpt[g], hi = gpt[g + 1];
    int n = hi - lo;
    int per = (n + 7) / 8;
    int s0 = lo + sp * per;
    int s1 = s0 + per; if (s1 > hi) s1 = hi;
    int lane = threadIdx.x & 63, wv = threadIdx.x >> 6;
    float acc = 0.f;
    for (int i = s0 + wv; i < s1; i += 4)
        acc += fmaxf(h[(long)i * 64 + lane], 0.f);
    if (acc != 0.f || wv == 0)
        atomicAdd(&sumh[g * 64 + lane], acc);
}

__global__ __launch_bounds__(256) void k_outgemm(const float* __restrict__ sumh,
                                                 const int* __restrict__ gpt,
                                                 const float* __restrict__ Wlin,
                                                 const float* __restrict__ blin,
                                                 float* __restrict__ out) {
    int idx = blockIdx.x * 256 + threadIdx.x;
    if (idx >= 64 * 32) return;
    int g = idx >> 5, o = idx & 31;
    int cnt = gpt[g + 1] - gpt[g];
    float acc = 0.f;
#pragma unroll 8
    for (int k = 0; k < 64; ++k)
        acc += sumh[g * 64 + k] * Wlin[k * 32 + o];
    out[idx] = (cnt > 0) ? (acc / (float)cnt + blin[o]) : 0.f;
}

extern "C" void kernel_launch(void* const* d_in, const int* in_sizes, int n_in,
                              void* d_out, int out_size, void* d_ws, size_t ws_size,
                              hipStream_t stream) {
    const float* pos    = (const float*)d_in[0];
    const int*   z      = (const int*)d_in[1];
    const int*   ei     = (const int*)d_in[2];
    const int*   batch  = (const int*)d_in[3];
    const float* emb    = (const float*)d_in[4];
    const float* t1_Win = (const float*)d_in[5];
    const float* t1_W1  = (const float*)d_in[6];
    const float* t1_b1  = (const float*)d_in[7];
    const float* t1_W2  = (const float*)d_in[8];
    const float* t1_b2  = (const float*)d_in[9];
    const float* t1_W3  = (const float*)d_in[10];
    const float* t1_b3  = (const float*)d_in[11];
    const float* t2_Win = (const float*)d_in[12];
    const float* t2_W1  = (const float*)d_in[13];
    const float* t2_b1  = (const float*)d_in[14];
    const float* t2_W2  = (const float*)d_in[15];
    const float* t2_b2  = (const float*)d_in[16];
    const float* t2_W3  = (const float*)d_in[17];
    const float* t2_b3  = (const float*)d_in[18];
    const float* Wlin   = (const float*)d_in[19];
    const float* blin   = (const float*)d_in[20];

    const int* srcI = ei;
    const int* dstI = ei + EE;

    char* ws = (char*)d_ws;
    size_t off = 0;
    auto alloc = [&](size_t bytes) -> void* {
        void* p = ws + off;
        off += (bytes + 255) / 256 * 256;
        return p;
    };
    float* bufH   = (float*)alloc((size_t)NN * 64 * 4);    // h master (fp32)
    float* accb   = (float*)alloc((size_t)NN * 64 * 4);    // dst-half+b1 / aliases xc
    u16*   hbx    = (u16*)alloc((size_t)NN * 128 * 2);     // h hi|lo combined
    u16*   agx    = (u16*)alloc((size_t)NN * 128 * 2);     // S hi|lo combined
    int*   rowptr = (int*)alloc((size_t)(NN + 1) * 4);
    int*   cursor = (int*)alloc((size_t)NN * 4);
    int*   srcc   = (int*)alloc((size_t)EE * 4);
    float* d2c    = (float*)alloc((size_t)(EE + 16) * 4);
    int*   gpt    = (int*)alloc(65 * 4);
    float* sumh   = (float*)alloc(64 * 64 * 4);
    u16*   WsA    = (u16*)alloc((size_t)8 * 40960 * 2);
    u16*   WsB    = (u16*)alloc((size_t)16384 * 2);

    u16* xc = (u16*)accb;   // x / relu(h) combined mirror (disjoint lifetime)

    // prologue: embed + CSR + weight swizzle + graph ranges
    k_embed<<<NN * 64 / 256, 256, 0, stream>>>(pos, z, emb, xc);
    hipMemsetAsync(cursor, 0, (size_t)NN * 4, stream);
    k_deg<<<(EE + 255) / 256, 256, 0, stream>>>(dstI, cursor);
    k_scan<<<1, 1024, 0, stream>>>(cursor, rowptr);
    hipMemcpyAsync(cursor, rowptr, (size_t)NN * 4, hipMemcpyDeviceToDevice, stream);
    k_scatter<<<(EE + 255) / 256, 256, 0, stream>>>(srcI, dstI, pos, cursor, srcc, d2c);
    k_swz<<<172032 / 256, 256, 0, stream>>>(t1_W1, t1_W2, t1_W3, t2_W1, t2_W2, t2_W3,
                                            t1_Win, t2_Win, WsA, WsB);
    k_granges<<<1, 128, 0, stream>>>(batch, gpt);

    // transformer 1
    k_proj_mfma<<<NTB, 256, 0, stream>>>(xc, WsB, bufH, hbx);
    k_dsthalf<<<NTB, 256, 0, stream>>>(hbx, WsA, t1_b1, accb);
    for (int l = 0; l < 4; ++l) {
        const u16* Wsl = WsA + (size_t)l * 40960;
        k_edges_mfma<<<EBLK, 256, 0, stream>>>(hbx, agx, d2c, rowptr, srcc, Wsl,
                                               t1_W1 + (size_t)l * 129 * 64, accb);
        const u16* WslN = (l < 3) ? (WsA + (size_t)(l + 1) * 40960) : nullptr;
        const float* b1N = (l < 3) ? (t1_b1 + (size_t)(l + 1) * 64) : nullptr;
        k_node2<<<NTB, 256, 0, stream>>>(bufH, hbx, agx, Wsl,
                                         t1_b2 + (size_t)l * 64, t1_b3 + (size_t)l * 64,
                                         rowptr, WslN, b1N, accb);
    }

    // transformer 2
    k_relu_split<<<NN * 64 / 256, 256, 0, stream>>>(bufH, xc);
    k_proj_mfma<<<NTB, 256, 0, stream>>>(xc, WsB + 8192, bufH, hbx);
    k_dsthalf<<<NTB, 256, 0, stream>>>(hbx, WsA + (size_t)4 * 40960, t2_b1, accb);
    for (int l = 0; l < 4; ++l) {
        const u16* Wsl = WsA + (size_t)(4 + l) * 40960;
        k_edges_mfma<<<EBLK, 256, 0, stream>>>(hbx, agx, d2c, rowptr, srcc, Wsl,
                                               t2_W1 + (size_t)l * 129 * 64, accb);
        const u16* WslN = (l < 3) ? (WsA + (size_t)(5 + l) * 40960) : nullptr;
        const float* b1N = (l < 3) ? (t2_b1 + (size_t)(l + 1) * 64) : nullptr;
        k_node2<<<NTB, 256, 0, stream>>>(bufH, hbx, agx, Wsl,
                                         t2_b2 + (size_t)l * 64, t2_b3 + (size_t)l * 64,
                                         rowptr, WslN, b1N, accb);
    }

    // pooled mean
    hipMemsetAsync(sumh, 0, 64 * 64 * 4, stream);
    k_sumrelu<<<64 * 8, 256, 0, stream>>>(bufH, gpt, sumh);
    k_outgemm<<<8, 256, 0, stream>>>(sumh, gpt, Wlin, blin, (float*)d_out);
}

// Round 7
// 1371.229 us; speedup vs baseline: 6.9064x; 1.1320x over previous
//
#include <hip/hip_runtime.h>
#include <hip/hip_bf16.h>

typedef unsigned short u16;
typedef unsigned int   u32;
typedef short bf16x8 __attribute__((ext_vector_type(8)));
typedef float f32x4  __attribute__((ext_vector_type(4)));

#define NN 100000
#define EE 800000
#define NTILE 6250            // NN/16
#define NTB   1563            // ceil(NTILE/4)
#define EBLK  2048            // persistent edge blocks
#define TOTW  (EBLK * 4)      // persistent edge waves
#define SCB   98              // scan blocks (98*1024 >= NN)

#define MFMA16(a,b,c) __builtin_amdgcn_mfma_f32_16x16x32_bf16(a,b,c,0,0,0)

__device__ __forceinline__ float b2f(u16 u) {
    u32 x = ((u32)u) << 16;
    return __uint_as_float(x);
}
__device__ __forceinline__ u16 f2b(float f) {
    __hip_bfloat16 h = __float2bfloat16(f);
    return *reinterpret_cast<u16*>(&h);
}
__device__ __forceinline__ void splt(float v, u16& hi, u16& lo) {
    hi = f2b(v);
    lo = f2b(v - b2f(hi));
}

// ---------------- embed: xc[i][0..63]=hi, [64..127]=lo of [pos|emb[z]] -------
__global__ __launch_bounds__(256) void k_embed(const float* __restrict__ pos,
                                               const int* __restrict__ z,
                                               const float* __restrict__ emb,
                                               u16* __restrict__ xc) {
    int gid = blockIdx.x * 256 + threadIdx.x;   // N*64 exactly
    int i = gid >> 6, f = gid & 63;
    float v = (f < 3) ? pos[i * 3 + f] : emb[(long)z[i] * 61 + (f - 3)];
    u16 hi, lo; splt(v, hi, lo);
    xc[(long)i * 128 + f] = hi;
    xc[(long)i * 128 + 64 + f] = lo;
}

// relu(h) -> combined hi/lo mirror
__global__ __launch_bounds__(256) void k_relu_split(const float* __restrict__ h,
                                                    u16* __restrict__ xc) {
    int gid = blockIdx.x * 256 + threadIdx.x;
    int i = gid >> 6, f = gid & 63;
    float v = fmaxf(h[gid], 0.f);
    u16 hi, lo; splt(v, hi, lo);
    xc[(long)i * 128 + f] = hi;
    xc[(long)i * 128 + 64 + f] = lo;
}

// ---------------- CSR build ----------------
__global__ __launch_bounds__(256) void k_deg(const int* __restrict__ dst,
                                             int* __restrict__ deg) {
    int e = blockIdx.x * 256 + threadIdx.x;
    if (e < EE) atomicAdd(&deg[dst[e]], 1);
}

// 3-phase parallel exclusive scan (coalesced, multi-CU)
__global__ __launch_bounds__(1024) void k_scanA(const int* __restrict__ deg,
                                                int* __restrict__ part) {
    __shared__ int s[1024];
    int i = blockIdx.x * 1024 + threadIdx.x;
    int v = (i < NN) ? deg[i] : 0;
    s[threadIdx.x] = v;
    __syncthreads();
    for (int off = 512; off > 0; off >>= 1) {
        if ((int)threadIdx.x < off) s[threadIdx.x] += s[threadIdx.x + off];
        __syncthreads();
    }
    if (threadIdx.x == 0) part[blockIdx.x] = s[0];
}

__global__ void k_scanB(int* __restrict__ part) {
    if (threadIdx.x == 0 && blockIdx.x == 0) {
        int run = 0;
        for (int b = 0; b < SCB; ++b) { int v = part[b]; part[b] = run; run += v; }
        part[SCB] = run;
    }
}

__global__ __launch_bounds__(1024) void k_scanC(const int* __restrict__ deg,
                                                const int* __restrict__ part,
                                                int* __restrict__ rowptr) {
    __shared__ int s[1024];
    int i = blockIdx.x * 1024 + threadIdx.x;
    int v = (i < NN) ? deg[i] : 0;
    s[threadIdx.x] = v;
    __syncthreads();
    for (int off = 1; off < 1024; off <<= 1) {
        int t = ((int)threadIdx.x >= off) ? s[threadIdx.x - off] : 0;
        __syncthreads();
        s[threadIdx.x] += t;
        __syncthreads();
    }
    int incl = s[threadIdx.x];
    if (i < NN) rowptr[i] = part[blockIdx.x] + incl - v;
    if (i == NN - 1) rowptr[NN] = part[SCB];
}

// scatter edges into CSR slots; computes d2 inline (segment order irrelevant)
__global__ __launch_bounds__(256) void k_scatter(const int* __restrict__ src,
                                                 const int* __restrict__ dst,
                                                 const float* __restrict__ pos,
                                                 int* __restrict__ cursor,
                                                 int* __restrict__ srcc,
                                                 float* __restrict__ d2c) {
    int e = blockIdx.x * 256 + threadIdx.x;
    if (e >= EE) return;
    int d = dst[e], s = src[e];
    int p = atomicAdd(&cursor[d], 1);
    srcc[p] = s;
    float dx = pos[s * 3 + 0] - pos[d * 3 + 0];
    float dy = pos[s * 3 + 1] - pos[d * 3 + 1];
    float dz = pos[s * 3 + 2] - pos[d * 3 + 2];
    d2c[p] = dx * dx + dy * dy + dz * dz;
}

// ---------------- weight swizzle (fp32 -> bf16 hi/lo B-frags) ----------------
// Layer block L (0..7) in WsA (u16): [W1hi 8192][W2hi 4096][W3hi 8192] then lo @+20480
// WsB: [Win1 hi 4096][Win1 lo 4096][Win2 hi 4096][Win2 lo 4096]
__global__ __launch_bounds__(256) void k_swz(const float* t1W1, const float* t1W2, const float* t1W3,
                                             const float* t2W1, const float* t2W2, const float* t2W3,
                                             const float* t1Win, const float* t2Win,
                                             u16* __restrict__ WsA, u16* __restrict__ WsB) {
    int gid = blockIdx.x * 256 + threadIdx.x;   // 172032 exactly
    if (gid < 163840) {
        int L = gid / 20480;
        int r = gid % 20480;
        const float* W1 = (L < 4 ? t1W1 : t2W1) + (size_t)(L & 3) * 129 * 64;
        const float* W2 = (L < 4 ? t1W2 : t2W2) + (size_t)(L & 3) * 64 * 64;
        const float* W3 = (L < 4 ? t1W3 : t2W3) + (size_t)(L & 3) * 128 * 64;
        float w;
        int rr, f, e, lane, j, row, col;
        if (r < 8192) { rr = r; f = rr >> 9; e = rr & 511; lane = e >> 3; j = e & 7;
            row = (f >> 2) * 32 + (lane >> 4) * 8 + j; col = (f & 3) * 16 + (lane & 15);
            w = W1[row * 64 + col];
        } else if (r < 12288) { rr = r - 8192; f = rr >> 9; e = rr & 511; lane = e >> 3; j = e & 7;
            row = (f >> 2) * 32 + (lane >> 4) * 8 + j; col = (f & 3) * 16 + (lane & 15);
            w = W2[row * 64 + col];
        } else { rr = r - 12288; f = rr >> 9; e = rr & 511; lane = e >> 3; j = e & 7;
            row = (f >> 2) * 32 + (lane >> 4) * 8 + j; col = (f & 3) * 16 + (lane & 15);
            w = W3[row * 64 + col];
        }
        u16 hi, lo; splt(w, hi, lo);
        WsA[(size_t)L * 40960 + r] = hi;
        WsA[(size_t)L * 40960 + 20480 + r] = lo;
    } else {
        int t = gid - 163840;
        int sel = (t < 4096) ? 0 : 1;
        int rr = t & 4095;
        const float* Win = sel ? t2Win : t1Win;
        int f = rr >> 9, e = rr & 511, lane = e >> 3, j = e & 7;
        int row = (f >> 2) * 32 + (lane >> 4) * 8 + j;
        int col = (f & 3) * 16 + (lane & 15);
        float w = Win[row * 64 + col];
        u16 hi, lo; splt(w, hi, lo);
        WsB[sel * 8192 + rr] = hi;
        WsB[sel * 8192 + 4096 + rr] = lo;
    }
}

// ---------------- dense proj: h = x @ Win (16 nodes/wave, bf16x2 split) -------
__global__ __launch_bounds__(256) void k_proj_mfma(const u16* __restrict__ xc,
                                                   const u16* __restrict__ WinS,
                                                   float* __restrict__ h,
                                                   u16* __restrict__ hbx) {
    int tile = blockIdx.x * 4 + (threadIdx.x >> 6);
    if (tile >= NTILE) return;
    int lane = threadIdx.x & 63, c = lane & 15, g = lane >> 4;
    int n0 = tile * 16, nr = n0 + c;
    const bf16x8* Wh = (const bf16x8*)WinS;
    const bf16x8* Wl = (const bf16x8*)(WinS + 4096);
    const bf16x8* p = (const bf16x8*)(xc + (long)nr * 128);
    bf16x8 A0h = p[g], A1h = p[g + 4], A0l = p[g + 8], A1l = p[g + 12];
#pragma unroll
    for (int nt = 0; nt < 4; ++nt) {
        f32x4 acc = {0.f, 0.f, 0.f, 0.f};
        acc = MFMA16(A0h, Wh[nt * 64 + lane], acc);
        acc = MFMA16(A1h, Wh[(4 + nt) * 64 + lane], acc);
        acc = MFMA16(A0l, Wh[nt * 64 + lane], acc);
        acc = MFMA16(A1l, Wh[(4 + nt) * 64 + lane], acc);
        acc = MFMA16(A0h, Wl[nt * 64 + lane], acc);
        acc = MFMA16(A1h, Wl[(4 + nt) * 64 + lane], acc);
#pragma unroll
        for (int r = 0; r < 4; ++r) {
            long n = n0 + 4 * g + r;
            h[n * 64 + nt * 16 + c] = acc[r];
            u16 hi, lo; splt(acc[r], hi, lo);
            hbx[n * 128 + nt * 16 + c] = hi;
            hbx[n * 128 + 64 + nt * 16 + c] = lo;
        }
    }
}

// ---------------- standalone dst-half of GEMM1 + b1 (layer 0 only) -----------
__global__ __launch_bounds__(256) void k_dsthalf(const u16* __restrict__ hbx,
                                                 const u16* __restrict__ Wsl,
                                                 const float* __restrict__ b1,
                                                 float* __restrict__ accb) {
    int tile = blockIdx.x * 4 + (threadIdx.x >> 6);
    if (tile >= NTILE) return;
    int lane = threadIdx.x & 63, c = lane & 15, g = lane >> 4;
    int n0 = tile * 16, nr = n0 + c;
    const bf16x8* W1h = (const bf16x8*)Wsl;
    const bf16x8* W1l = (const bf16x8*)(Wsl + 20480);
    const bf16x8* p = (const bf16x8*)(hbx + (long)nr * 128);
    bf16x8 A0h = p[g], A1h = p[g + 4], A0l = p[g + 8], A1l = p[g + 12];
#pragma unroll
    for (int nt = 0; nt < 4; ++nt) {
        float bv = b1[nt * 16 + c];
        f32x4 acc = {bv, bv, bv, bv};
        acc = MFMA16(A0h, W1h[(8 + nt) * 64 + lane], acc);
        acc = MFMA16(A1h, W1h[(12 + nt) * 64 + lane], acc);
        acc = MFMA16(A0l, W1h[(8 + nt) * 64 + lane], acc);
        acc = MFMA16(A1l, W1h[(12 + nt) * 64 + lane], acc);
        acc = MFMA16(A0h, W1l[(8 + nt) * 64 + lane], acc);
        acc = MFMA16(A1h, W1l[(12 + nt) * 64 + lane], acc);
#pragma unroll
        for (int r = 0; r < 4; ++r)
            accb[(long)(n0 + 4 * g + r) * 64 + nt * 16 + c] = acc[r];
    }
}

// ---------------- edge kernel: GEMM1 + relu + row-sum -> S[node] -------------
// persistent: wave w handles nodes w, w+TOTW, ... ; no LDS, no per-edge GEMM2
__global__ __launch_bounds__(256) void k_edges_mfma(const u16* __restrict__ hbx,
                                                    u16* __restrict__ agx,
                                                    const float* __restrict__ d2c,
                                                    const int* __restrict__ rowptr,
                                                    const int* __restrict__ srcc,
                                                    const u16* __restrict__ Wsl,
                                                    const float* __restrict__ W1f,
                                                    const float* __restrict__ accb) {
    int lane = threadIdx.x & 63;
    int wid = blockIdx.x * 4 + (threadIdx.x >> 6);
    int c = lane & 15, g = lane >> 4;
    const bf16x8* W1H = (const bf16x8*)Wsl;
    const bf16x8* W1L = (const bf16x8*)(Wsl + 20480);
    // stationary: src-half of W1, hi+lo (16 frags, register-resident)
    bf16x8 w1h[2][4], w1l[2][4];
#pragma unroll
    for (int ks = 0; ks < 2; ++ks)
#pragma unroll
        for (int nt = 0; nt < 4; ++nt) {
            w1h[ks][nt] = W1H[(ks * 4 + nt) * 64 + lane];
            w1l[ks][nt] = W1L[(ks * 4 + nt) * 64 + lane];
        }
    float wdc[4];
#pragma unroll
    for (int nt = 0; nt < 4; ++nt) wdc[nt] = W1f[128 * 64 + nt * 16 + c];

    for (int node = wid; node < NN; node += TOTW) {
        float base_c[4];
#pragma unroll
        for (int nt = 0; nt < 4; ++nt)
            base_c[nt] = accb[(long)node * 64 + nt * 16 + c];
        int e0 = rowptr[node], e1 = rowptr[node + 1];
        f32x4 z = {0.f, 0.f, 0.f, 0.f};
        f32x4 acc[4] = {z, z, z, z};

        for (int te = e0; te < e1; te += 16) {
            int t = te + c;
            if (t > e1 - 1) t = e1 - 1;
            int s = srcc[t];
            const bf16x8* sp = (const bf16x8*)(hbx + (long)s * 128);
            bf16x8 A0h = sp[g], A1h = sp[g + 4], A0l = sp[g + 8], A1l = sp[g + 12];
            float dq[4];
#pragma unroll
            for (int r = 0; r < 4; ++r) dq[r] = d2c[te + 4 * g + r];
            int rem = e1 - te;
#pragma unroll
            for (int nt = 0; nt < 4; ++nt) {
                f32x4 ci;
#pragma unroll
                for (int r = 0; r < 4; ++r) ci[r] = base_c[nt] + dq[r] * wdc[nt];
                ci = MFMA16(A0h, w1h[0][nt], ci);
                ci = MFMA16(A1h, w1h[1][nt], ci);
                ci = MFMA16(A0l, w1h[0][nt], ci);
                ci = MFMA16(A1l, w1h[1][nt], ci);
                ci = MFMA16(A0h, w1l[0][nt], ci);
                ci = MFMA16(A1h, w1l[1][nt], ci);
#pragma unroll
                for (int r = 0; r < 4; ++r)
                    acc[nt][r] += (4 * g + r < rem) ? fmaxf(ci[r], 0.f) : 0.f;
            }
        }
        // reduce rows (edges) -> per-col sums; lane owns col==lane
        float sv[4];
#pragma unroll
        for (int nt = 0; nt < 4; ++nt) {
            float s = acc[nt][0] + acc[nt][1] + acc[nt][2] + acc[nt][3];
            s += __shfl_xor(s, 16);
            s += __shfl_xor(s, 32);
            sv[nt] = s;
        }
        float v = sv[0];
        v = (g == 1) ? sv[1] : v;
        v = (g == 2) ? sv[2] : v;
        v = (g == 3) ? sv[3] : v;
        u16 hi, lo; splt(v, hi, lo);
        agx[(long)node * 128 + lane] = hi;
        agx[(long)node * 128 + 64 + lane] = lo;
    }
}

// ---------------- fused dense kernel: agg = S@W2 + deg*b2 ; h += relu([h,agg]@W3+b3)
// ; optionally accb_next = h_new @ W1next(dst-half) + b1next
__global__ __launch_bounds__(256) void k_node2(float* __restrict__ h,
                                               u16* __restrict__ hbx,
                                               const u16* __restrict__ agx,
                                               const u16* __restrict__ Wsl,
                                               const float* __restrict__ b2,
                                               const float* __restrict__ b3,
                                               const int* __restrict__ rowptr,
                                               const u16* __restrict__ WslN,
                                               const float* __restrict__ b1N,
                                               float* __restrict__ accb) {
    __shared__ u16 th[4][16 * 72];
    __shared__ u16 tl[4][16 * 72];
    int w = threadIdx.x >> 6, lane = threadIdx.x & 63;
    int tile = blockIdx.x * 4 + w;
    if (tile >= NTILE) return;
    int c = lane & 15, g = lane >> 4;
    int n0 = tile * 16, nr = n0 + c;
    u16* lh = th[w];
    u16* ll = tl[w];

    const bf16x8* W2H = (const bf16x8*)(Wsl + 8192);
    const bf16x8* W2L = (const bf16x8*)(Wsl + 28672);
    const bf16x8* W3H = (const bf16x8*)(Wsl + 12288);
    const bf16x8* W3L = (const bf16x8*)(Wsl + 32768);

    const bf16x8* sp = (const bf16x8*)(agx + (long)nr * 128);
    bf16x8 S0h = sp[g], S1h = sp[g + 4], S0l = sp[g + 8], S1l = sp[g + 12];
    const bf16x8* hp = (const bf16x8*)(hbx + (long)nr * 128);
    bf16x8 H0h = hp[g], H1h = hp[g + 4], H0l = hp[g + 8], H1l = hp[g + 12];

    float dg[4];
#pragma unroll
    for (int r = 0; r < 4; ++r) {
        int n = n0 + 4 * g + r;
        dg[r] = (float)(rowptr[n + 1] - rowptr[n]);
    }

    // GEMM2: agg (C-layout) -> LDS transpose planes
#pragma unroll
    for (int nt = 0; nt < 4; ++nt) {
        float b2c = b2[nt * 16 + c];
        f32x4 a = {dg[0] * b2c, dg[1] * b2c, dg[2] * b2c, dg[3] * b2c};
        a = MFMA16(S0h, W2H[nt * 64 + lane], a);
        a = MFMA16(S1h, W2H[(4 + nt) * 64 + lane], a);
        a = MFMA16(S0l, W2H[nt * 64 + lane], a);
        a = MFMA16(S1l, W2H[(4 + nt) * 64 + lane], a);
        a = MFMA16(S0h, W2L[nt * 64 + lane], a);
        a = MFMA16(S1h, W2L[(4 + nt) * 64 + lane], a);
#pragma unroll
        for (int r = 0; r < 4; ++r) {
            u16 hi, lo; splt(a[r], hi, lo);
            lh[(4 * g + r) * 72 + nt * 16 + c] = hi;
            ll[(4 * g + r) * 72 + nt * 16 + c] = lo;
        }
    }
    bf16x8 G0h = *(const bf16x8*)(lh + c * 72 + g * 8);
    bf16x8 G1h = *(const bf16x8*)(lh + c * 72 + 32 + g * 8);
    bf16x8 G0l = *(const bf16x8*)(ll + c * 72 + g * 8);
    bf16x8 G1l = *(const bf16x8*)(ll + c * 72 + 32 + g * 8);

    // GEMM3: u = [h, agg] @ W3 + b3
    f32x4 u4[4];
#pragma unroll
    for (int nt = 0; nt < 4; ++nt) {
        float bv = b3[nt * 16 + c];
        f32x4 u = {bv, bv, bv, bv};
        u = MFMA16(H0h, W3H[nt * 64 + lane], u);
        u = MFMA16(H1h, W3H[(4 + nt) * 64 + lane], u);
        u = MFMA16(G0h, W3H[(8 + nt) * 64 + lane], u);
        u = MFMA16(G1h, W3H[(12 + nt) * 64 + lane], u);
        u = MFMA16(H0l, W3H[nt * 64 + lane], u);
        u = MFMA16(H1l, W3H[(4 + nt) * 64 + lane], u);
        u = MFMA16(G0l, W3H[(8 + nt) * 64 + lane], u);
        u = MFMA16(G1l, W3H[(12 + nt) * 64 + lane], u);
        u = MFMA16(H0h, W3L[nt * 64 + lane], u);
        u = MFMA16(H1h, W3L[(4 + nt) * 64 + lane], u);
        u = MFMA16(G0h, W3L[(8 + nt) * 64 + lane], u);
        u = MFMA16(G1h, W3L[(12 + nt) * 64 + lane], u);
        u4[nt] = u;
    }

    // h update + hbx write + stash h_new for next-layer dst-half
#pragma unroll
    for (int nt = 0; nt < 4; ++nt)
#pragma unroll
        for (int r = 0; r < 4; ++r) {
            long n = n0 + 4 * g + r;
            long idx = n * 64 + nt * 16 + c;
            float hn = h[idx] + fmaxf(u4[nt][r], 0.f);
            h[idx] = hn;
            u16 hi, lo; splt(hn, hi, lo);
            hbx[n * 128 + nt * 16 + c] = hi;
            hbx[n * 128 + 64 + nt * 16 + c] = lo;
            lh[(4 * g + r) * 72 + nt * 16 + c] = hi;
            ll[(4 * g + r) * 72 + nt * 16 + c] = lo;
        }

    if (WslN) {
        bf16x8 N0h = *(const bf16x8*)(lh + c * 72 + g * 8);
        bf16x8 N1h = *(const bf16x8*)(lh + c * 72 + 32 + g * 8);
        bf16x8 N0l = *(const bf16x8*)(ll + c * 72 + g * 8);
        bf16x8 N1l = *(const bf16x8*)(ll + c * 72 + 32 + g * 8);
        const bf16x8* W1h = (const bf16x8*)WslN;
        const bf16x8* W1l = (const bf16x8*)(WslN + 20480);
#pragma unroll
        for (int nt = 0; nt < 4; ++nt) {
            float bv = b1N[nt * 16 + c];
            f32x4 a = {bv, bv, bv, bv};
            a = MFMA16(N0h, W1h[(8 + nt) * 64 + lane], a);
            a = MFMA16(N1h, W1h[(12 + nt) * 64 + lane], a);
            a = MFMA16(N0l, W1h[(8 + nt) * 64 + lane], a);
            a = MFMA16(N1l, W1h[(12 + nt) * 64 + lane], a);
            a = MFMA16(N0h, W1l[(8 + nt) * 64 + lane], a);
            a = MFMA16(N1h, W1l[(12 + nt) * 64 + lane], a);
#pragma unroll
            for (int r = 0; r < 4; ++r)
                accb[(long)(n0 + 4 * g + r) * 64 + nt * 16 + c] = a[r];
        }
    }
}

// ---------------- pooling: atomic-light via sorted-batch ranges ---------------
__global__ void k_granges(const int* __restrict__ batch, int* __restrict__ gpt) {
    int g = blockIdx.x * blockDim.x + threadIdx.x;
    if (g > 64) return;
    int lo = 0, hi = NN;
    while (lo < hi) {
        int mid = (lo + hi) >> 1;
        if (batch[mid] < g) lo = mid + 1; else hi = mid;
    }
    gpt[g] = lo;
}

__global__ __launch_bounds__(256) void k_sumrelu(const float* __restrict__ h,
                                                 const int* __restrict__ gpt,
                                                 float* __restrict__ sumh) {
    int g = blockIdx.x >> 3, sp = blockIdx.x & 7;
    int lo = gpt[g], hi = gpt[g + 1];
    int n = hi - lo;
    int per = (n + 7) / 8;
    int s0 = lo + sp * per;
    int s1 = s0 + per; if (s1 > hi) s1 = hi;
    int lane = threadIdx.x & 63, wv = threadIdx.x >> 6;
    float acc = 0.f;
    for (int i = s0 + wv; i < s1; i += 4)
        acc += fmaxf(h[(long)i * 64 + lane], 0.f);
    if (acc != 0.f || wv == 0)
        atomicAdd(&sumh[g * 64 + lane], acc);
}

__global__ __launch_bounds__(256) void k_outgemm(const float* __restrict__ sumh,
                                                 const int* __restrict__ gpt,
                                                 const float* __restrict__ Wlin,
                                                 const float* __restrict__ blin,
                                                 float* __restrict__ out) {
    int idx = blockIdx.x * 256 + threadIdx.x;
    if (idx >= 64 * 32) return;
    int g = idx >> 5, o = idx & 31;
    int cnt = gpt[g + 1] - gpt[g];
    float acc = 0.f;
#pragma unroll 8
    for (int k = 0; k < 64; ++k)
        acc += sumh[g * 64 + k] * Wlin[k * 32 + o];
    out[idx] = (cnt > 0) ? (acc / (float)cnt + blin[o]) : 0.f;
}

extern "C" void kernel_launch(void* const* d_in, const int* in_sizes, int n_in,
                              void* d_out, int out_size, void* d_ws, size_t ws_size,
                              hipStream_t stream) {
    const float* pos    = (const float*)d_in[0];
    const int*   z      = (const int*)d_in[1];
    const int*   ei     = (const int*)d_in[2];
    const int*   batch  = (const int*)d_in[3];
    const float* emb    = (const float*)d_in[4];
    const float* t1_Win = (const float*)d_in[5];
    const float* t1_W1  = (const float*)d_in[6];
    const float* t1_b1  = (const float*)d_in[7];
    const float* t1_W2  = (const float*)d_in[8];
    const float* t1_b2  = (const float*)d_in[9];
    const float* t1_W3  = (const float*)d_in[10];
    const float* t1_b3  = (const float*)d_in[11];
    const float* t2_Win = (const float*)d_in[12];
    const float* t2_W1  = (const float*)d_in[13];
    const float* t2_b1  = (const float*)d_in[14];
    const float* t2_W2  = (const float*)d_in[15];
    const float* t2_b2  = (const float*)d_in[16];
    const float* t2_W3  = (const float*)d_in[17];
    const float* t2_b3  = (const float*)d_in[18];
    const float* Wlin   = (const float*)d_in[19];
    const float* blin   = (const float*)d_in[20];

    const int* srcI = ei;
    const int* dstI = ei + EE;

    char* ws = (char*)d_ws;
    size_t off = 0;
    auto alloc = [&](size_t bytes) -> void* {
        void* p = ws + off;
        off += (bytes + 255) / 256 * 256;
        return p;
    };
    float* bufH   = (float*)alloc((size_t)NN * 64 * 4);    // h master (fp32)
    float* accb   = (float*)alloc((size_t)NN * 64 * 4);    // dst-half+b1 / aliases xc
    u16*   hbx    = (u16*)alloc((size_t)NN * 128 * 2);     // h hi|lo combined
    u16*   agx    = (u16*)alloc((size_t)NN * 128 * 2);     // S hi|lo combined
    int*   rowptr = (int*)alloc((size_t)(NN + 1) * 4);
    int*   cursor = (int*)alloc((size_t)NN * 4);
    int*   srcc   = (int*)alloc((size_t)EE * 4);
    float* d2c    = (float*)alloc((size_t)(EE + 16) * 4);
    int*   gpt    = (int*)alloc(65 * 4);
    float* sumh   = (float*)alloc(64 * 64 * 4);
    int*   part   = (int*)alloc((SCB + 1) * 4);
    u16*   WsA    = (u16*)alloc((size_t)8 * 40960 * 2);
    u16*   WsB    = (u16*)alloc((size_t)16384 * 2);

    u16* xc = (u16*)accb;   // x / relu(h) combined mirror (disjoint lifetime)

    // prologue: embed + CSR + weight swizzle + graph ranges
    k_embed<<<NN * 64 / 256, 256, 0, stream>>>(pos, z, emb, xc);
    hipMemsetAsync(cursor, 0, (size_t)NN * 4, stream);
    k_deg<<<(EE + 255) / 256, 256, 0, stream>>>(dstI, cursor);
    k_scanA<<<SCB, 1024, 0, stream>>>(cursor, part);
    k_scanB<<<1, 64, 0, stream>>>(part);
    k_scanC<<<SCB, 1024, 0, stream>>>(cursor, part, rowptr);
    hipMemcpyAsync(cursor, rowptr, (size_t)NN * 4, hipMemcpyDeviceToDevice, stream);
    k_scatter<<<(EE + 255) / 256, 256, 0, stream>>>(srcI, dstI, pos, cursor, srcc, d2c);
    k_swz<<<172032 / 256, 256, 0, stream>>>(t1_W1, t1_W2, t1_W3, t2_W1, t2_W2, t2_W3,
                                            t1_Win, t2_Win, WsA, WsB);
    k_granges<<<1, 128, 0, stream>>>(batch, gpt);

    // transformer 1
    k_proj_mfma<<<NTB, 256, 0, stream>>>(xc, WsB, bufH, hbx);
    k_dsthalf<<<NTB, 256, 0, stream>>>(hbx, WsA, t1_b1, accb);
    for (int l = 0; l < 4; ++l) {
        const u16* Wsl = WsA + (size_t)l * 40960;
        k_edges_mfma<<<EBLK, 256, 0, stream>>>(hbx, agx, d2c, rowptr, srcc, Wsl,
                                               t1_W1 + (size_t)l * 129 * 64, accb);
        const u16* WslN = (l < 3) ? (WsA + (size_t)(l + 1) * 40960) : nullptr;
        const float* b1N = (l < 3) ? (t1_b1 + (size_t)(l + 1) * 64) : nullptr;
        k_node2<<<NTB, 256, 0, stream>>>(bufH, hbx, agx, Wsl,
                                         t1_b2 + (size_t)l * 64, t1_b3 + (size_t)l * 64,
                                         rowptr, WslN, b1N, accb);
    }

    // transformer 2
    k_relu_split<<<NN * 64 / 256, 256, 0, stream>>>(bufH, xc);
    k_proj_mfma<<<NTB, 256, 0, stream>>>(xc, WsB + 8192, bufH, hbx);
    k_dsthalf<<<NTB, 256, 0, stream>>>(hbx, WsA + (size_t)4 * 40960, t2_b1, accb);
    for (int l = 0; l < 4; ++l) {
        const u16* Wsl = WsA + (size_t)(4 + l) * 40960;
        k_edges_mfma<<<EBLK, 256, 0, stream>>>(hbx, agx, d2c, rowptr, srcc, Wsl,
                                               t2_W1 + (size_t)l * 129 * 64, accb);
        const u16* WslN = (l < 3) ? (WsA + (size_t)(5 + l) * 40960) : nullptr;
        const float* b1N = (l < 3) ? (t2_b1 + (size_t)(l + 1) * 64) : nullptr;
        k_node2<<<NTB, 256, 0, stream>>>(bufH, hbx, agx, Wsl,
                                         t2_b2 + (size_t)l * 64, t2_b3 + (size_t)l * 64,
                                         rowptr, WslN, b1N, accb);
    }

    // pooled mean
    hipMemsetAsync(sumh, 0, 64 * 64 * 4, stream);
    k_sumrelu<<<64 * 8, 256, 0, stream>>>(bufH, gpt, sumh);
    k_outgemm<<<8, 256, 0, stream>>>(sumh, gpt, Wlin, blin, (float*)d_out);
}